// Round 8
// baseline (297.643 us; speedup 1.0000x reference)
//
#include <hip/hip_runtime.h>
#include <hip/hip_bf16.h>
#include <stdint.h>

#define B_ 2
#define N_ 4096
#define D_ 128
#define H_ 4
#define HID_ 32
#define EN_ 16
#define ALPHA_ 0.2f
#define S1_ 4
#define S2_ 4
#define LOG2E_ 1.4426950408889634f

typedef __attribute__((ext_vector_type(8))) _Float16 f16x8;
typedef __attribute__((ext_vector_type(4))) float f32x4;
typedef __attribute__((ext_vector_type(8))) unsigned short u16x8;

__device__ __forceinline__ unsigned short f2h(float v) {
    _Float16 h = (_Float16)v;
    return *(unsigned short*)&h;
}

// ---------- prep: layer-1 projection only. 1024 blocks.
__global__ __launch_bounds__(256) void prep_kernel(
    const float* __restrict__ fea, const float* __restrict__ Wh,
    const float* __restrict__ a_heads,
    float* __restrict__ wh1, float* __restrict__ wh2,
    float* __restrict__ cmax1, unsigned short* __restrict__ whTt)
{
    __shared__ float xs[32][132];          // 16.9 KB
    __shared__ float WT[32][132];          // 16.9 KB
    __shared__ float Wa[2][128];
    __shared__ float as_[2 * HID_];
    __shared__ unsigned short ts[32][32];  // [d][r]
    __shared__ float rmax[32];
    const int tid = threadIdx.x;
    const int l0 = blockIdx.x;
    const int ib = l0 & 127, h = (l0 >> 7) & 3, b = l0 >> 9;
    const int i0 = ib * 32;
    const float* Wp = Wh + (size_t)h * D_ * HID_;
    for (int l = tid; l < 1024; l += 256) {          // W[k][d] -> WT[d][k]
        float4 w4 = *(const float4*)(Wp + l * 4);
        int k = l >> 3, d = (l & 7) * 4;
        WT[d][k] = w4.x; WT[d + 1][k] = w4.y; WT[d + 2][k] = w4.z; WT[d + 3][k] = w4.w;
    }
    if (tid < 2 * HID_) as_[tid] = a_heads[h * 2 * HID_ + tid];
    const float* xp = fea + ((size_t)b * N_ + i0) * D_;
    for (int l = tid; l < 1024; l += 256) {
        int r = l >> 5, k4 = (l & 31) * 4;
        *(float4*)&xs[r][k4] = *(const float4*)(xp + r * D_ + k4);
    }
    __syncthreads();
    // Wa[j][k] = sum_d W[k][d]*a[j*HID+d]
    {
        const int k = tid & 127, j = tid >> 7;
        const float* wr = Wp + k * HID_;
        const float* aw = &as_[j * HID_];
        float s = 0.f;
#pragma unroll
        for (int d = 0; d < HID_; d += 4) {
            float4 w4 = *(const float4*)(wr + d);
            s += w4.x * aw[d] + w4.y * aw[d + 1] + w4.z * aw[d + 2] + w4.w * aw[d + 3];
        }
        Wa[j][k] = s;
    }
    const int c = tid & 15, rg = (tid >> 4) * 2;     // rows rg,rg+1; cols c,c+16
    float a0[2] = {0.f, 0.f}, a1[2] = {0.f, 0.f};
#pragma unroll 8
    for (int k = 0; k < D_; k += 4) {
        float4 w0 = *(float4*)&WT[c][k];
        float4 w1 = *(float4*)&WT[c + 16][k];
#pragma unroll
        for (int i = 0; i < 2; ++i) {
            float4 x4 = *(float4*)&xs[rg + i][k];
            a0[i] += x4.x * w0.x + x4.y * w0.y + x4.z * w0.z + x4.w * w0.w;
            a1[i] += x4.x * w1.x + x4.y * w1.y + x4.z * w1.z + x4.w * w1.w;
        }
    }
#pragma unroll
    for (int i = 0; i < 2; ++i) {
        ts[c][rg + i] = f2h(a0[i]);
        ts[c + 16][rg + i] = f2h(a1[i]);
    }
    __syncthreads();                                 // Wa + ts ready
    {
        const int row = tid >> 3, q = tid & 7;       // 32 rows x 8 threads
        float d1 = 0.f, d2 = 0.f;
#pragma unroll
        for (int k = q * 16; k < q * 16 + 16; k += 4) {
            float4 x4 = *(float4*)&xs[row][k];
            float4 u = *(float4*)&Wa[0][k];
            float4 v = *(float4*)&Wa[1][k];
            d1 += x4.x * u.x + x4.y * u.y + x4.z * u.z + x4.w * u.w;
            d2 += x4.x * v.x + x4.y * v.y + x4.z * v.z + x4.w * v.w;
        }
        d1 += __shfl_xor(d1, 1); d1 += __shfl_xor(d1, 2); d1 += __shfl_xor(d1, 4);
        d2 += __shfl_xor(d2, 1); d2 += __shfl_xor(d2, 2); d2 += __shfl_xor(d2, 4);
        if (q == 0) {
            const size_t o = (size_t)(b * H_ + h) * N_ + i0 + row;
            wh1[o] = d1 * LOG2E_;
            wh2[o] = d2 * LOG2E_;
            rmax[row] = d2 * LOG2E_;
        }
    }
    __syncthreads();
    if (tid < 128) {                                 // whT tile out (1024 halfwords)
        const int d = tid >> 2, part = (tid & 3) * 8;
        unsigned short* dst = whTt + ((size_t)(b * H_ + h) * 64 + (i0 >> 6)) * 2048
                            + d * 64 + (i0 & 63) + part;
        *(u16x8*)dst = *(u16x8*)&ts[d][part];
    }
    if (tid < 32) {
        float mx = rmax[tid];
#pragma unroll
        for (int off = 16; off; off >>= 1) mx = fmaxf(mx, __shfl_xor(mx, off));
        if (tid == 0) cmax1[(size_t)(b * H_ + h) * 128 + ib] = mx;
    }
}

// ---------- layer-1 fused MFMA attention.
// R8 (counters-driven): attn1 measured 112us with VALUBusy=32%, MfmaUtil=4%,
// HBM=11% -> latency-bound on per-iteration global (L2) loads. Fixes:
// (a) main loop software-prefetches the next t-tile's 4 whT f16x8 + 4 wh2
//     float4 into registers (one iteration of compute hides ~200cy L2),
// (b) mask-build batches 8 loads in flight (2 rows x 4 chunks).
// VGPR was 64 of ~128 affordable -> prefetch regs are free occupancy-wise.
__global__ __launch_bounds__(256) void attn1_kernel(
    const float* __restrict__ adj, unsigned long long* __restrict__ mask,
    const unsigned short* __restrict__ whT,
    const float* __restrict__ wh1, const float* __restrict__ wh2,
    const float* __restrict__ cmax1,
    float* __restrict__ x2p, float* __restrict__ l1p)
{
    __shared__ unsigned long long mask_s[32][17];
    __shared__ float Btab[H_][2][1024];    // 32 KB: per-head (B, B') tables
    const int b = blockIdx.z, split = blockIdx.y, i0 = blockIdx.x * 32;
    const int tid = threadIdx.x, lane = tid & 63, h = tid >> 6;
    const int m = lane & 15, quad = lane >> 4;
    // ---- build mask bits from adj: 2 rows per batch -> 8 loads in flight ----
    {
        for (int rr = 0; rr < 8; rr += 2) {
            const int row = h * 8 + rr;
            const float* ar0 = adj + ((size_t)b * N_ + i0 + row) * N_ + split * 1024;
            const float* ar1 = ar0 + N_;
            float4 va[4], vb[4];
#pragma unroll
            for (int c = 0; c < 4; ++c) {
                va[c] = *(const float4*)(ar0 + c * 256 + lane * 4);
                vb[c] = *(const float4*)(ar1 + c * 256 + lane * 4);
            }
            unsigned long long* mrow0 = mask + ((size_t)b * N_ + i0 + row) * 64
                                      + split * 16;
            unsigned long long* mrow1 = mrow0 + 64;
#pragma unroll
            for (int c = 0; c < 4; ++c) {
                unsigned long long b0 = __ballot(va[c].x != 0.f);
                unsigned long long b1 = __ballot(va[c].y != 0.f);
                unsigned long long b2 = __ballot(va[c].z != 0.f);
                unsigned long long b3 = __ballot(va[c].w != 0.f);
                if (lane == 0) {
                    mask_s[row][c * 4 + 0] = b0; mask_s[row][c * 4 + 1] = b1;
                    mask_s[row][c * 4 + 2] = b2; mask_s[row][c * 4 + 3] = b3;
                    ulonglong2 w01 = {b0, b1}, w23 = {b2, b3};
                    *(ulonglong2*)(mrow0 + c * 4) = w01;
                    *(ulonglong2*)(mrow0 + c * 4 + 2) = w23;
                }
            }
#pragma unroll
            for (int c = 0; c < 4; ++c) {
                unsigned long long b0 = __ballot(vb[c].x != 0.f);
                unsigned long long b1 = __ballot(vb[c].y != 0.f);
                unsigned long long b2 = __ballot(vb[c].z != 0.f);
                unsigned long long b3 = __ballot(vb[c].w != 0.f);
                if (lane == 0) {
                    mask_s[row + 1][c * 4 + 0] = b0; mask_s[row + 1][c * 4 + 1] = b1;
                    mask_s[row + 1][c * 4 + 2] = b2; mask_s[row + 1][c * 4 + 3] = b3;
                    ulonglong2 w01 = {b0, b1}, w23 = {b2, b3};
                    *(ulonglong2*)(mrow1 + c * 4) = w01;
                    *(ulonglong2*)(mrow1 + c * 4 + 2) = w23;
                }
            }
        }
    }
    const float* cm = cmax1 + (size_t)(b * H_ + h) * 128;
    float Mh = fmaxf(cm[lane], cm[lane + 64]);
#pragma unroll
    for (int off = 32; off; off >>= 1) Mh = fmaxf(Mh, __shfl_xor(Mh, off));
    const size_t bhN = (size_t)(b * H_ + h) * N_;
    // fill this head's (B, B') table: 1024 j's, 16 per lane
    const float* w2g = wh2 + bhN + split * 1024;
#pragma unroll
    for (int g = 0; g < 4; ++g) {
        float4 v = *(const float4*)(w2g + g * 256 + lane * 4);
        float4 eb, ep;
        eb.x = __builtin_amdgcn_exp2f(v.x - Mh);
        eb.y = __builtin_amdgcn_exp2f(v.y - Mh);
        eb.z = __builtin_amdgcn_exp2f(v.z - Mh);
        eb.w = __builtin_amdgcn_exp2f(v.w - Mh);
        ep.x = __builtin_amdgcn_exp2f(ALPHA_ * (v.x - Mh));
        ep.y = __builtin_amdgcn_exp2f(ALPHA_ * (v.y - Mh));
        ep.z = __builtin_amdgcn_exp2f(ALPHA_ * (v.z - Mh));
        ep.w = __builtin_amdgcn_exp2f(ALPHA_ * (v.w - Mh));
        *(float4*)&Btab[h][0][g * 256 + lane * 4] = eb;
        *(float4*)&Btab[h][1][g * 256 + lane * 4] = ep;
    }
    const float w1r0 = wh1[bhN + i0 + m];
    const float w1r1 = wh1[bhN + i0 + 16 + m];
    const float sb0 = w1r0 + Mh, sb1 = w1r1 + Mh;
    const float mr0 = fmaxf(sb0, ALPHA_ * sb0);
    const float mr1 = fmaxf(sb1, ALPHA_ * sb1);
    const float th0 = -w1r0, th1 = -w1r1;
    const float Fp0 = __builtin_amdgcn_exp2f(sb0 - mr0);
    const float Fn0 = __builtin_amdgcn_exp2f(ALPHA_ * sb0 - mr0);
    const float Fp1 = __builtin_amdgcn_exp2f(sb1 - mr1);
    const float Fn1 = __builtin_amdgcn_exp2f(ALPHA_ * sb1 - mr1);
    const float* wvb = wh2 + bhN + split * 1024 + quad * 8;
    const unsigned short* bpb = whT + (size_t)(b * H_ + h) * 131072
                              + (size_t)split * 16 * 2048 + m * 64 + quad * 8;
    f32x4 a00 = {0.f,0.f,0.f,0.f}, a01 = {0.f,0.f,0.f,0.f}, a02 = {0.f,0.f,0.f,0.f};
    f32x4 a10 = {0.f,0.f,0.f,0.f}, a11 = {0.f,0.f,0.f,0.f}, a12 = {0.f,0.f,0.f,0.f};
    f16x8 ones;
#pragma unroll
    for (int q = 0; q < 8; ++q) ones[q] = (_Float16)1.0f;
    // prologue: load t=0 tile into current regs (overlaps barrier)
    f16x8 cbA0 = *(const f16x8*)(bpb);
    f16x8 cbB0 = *(const f16x8*)(bpb + 32);
    f16x8 cbA1 = *(const f16x8*)(bpb + 1024);
    f16x8 cbB1 = *(const f16x8*)(bpb + 1056);
    float4 cu0 = *(const float4*)(wvb);
    float4 cu1 = *(const float4*)(wvb + 4);
    float4 cv0 = *(const float4*)(wvb + 32);
    float4 cv1 = *(const float4*)(wvb + 36);
    __syncthreads();

    for (int c = 0; c < 4; ++c) {
#pragma unroll
        for (int q4 = 0; q4 < 4; ++q4) {
            const int t = c * 4 + q4;
            // ---- prefetch t+1 tile (clamped; t=15 re-reads its own tile) ----
            const int tn = (t < 15) ? t + 1 : 15;
            const unsigned short* bpn = bpb + (size_t)tn * 2048;
            const float* nwn = wvb + tn * 64;
            f16x8 nbA0 = *(const f16x8*)(bpn);
            f16x8 nbB0 = *(const f16x8*)(bpn + 32);
            f16x8 nbA1 = *(const f16x8*)(bpn + 1024);
            f16x8 nbB1 = *(const f16x8*)(bpn + 1056);
            float4 nu0 = *(const float4*)(nwn);
            float4 nu1 = *(const float4*)(nwn + 4);
            float4 nv0 = *(const float4*)(nwn + 32);
            float4 nv1 = *(const float4*)(nwn + 36);
            // ---- mask dwords for t (LDS broadcast) ----
            const int half = q4 >> 1;
            unsigned int pw0, pw1, pw2, pw3, qw0, qw1, qw2, qw3;
            pw0 = ((const unsigned int*)&mask_s[m][c*4+0])[half];
            pw1 = ((const unsigned int*)&mask_s[m][c*4+1])[half];
            pw2 = ((const unsigned int*)&mask_s[m][c*4+2])[half];
            pw3 = ((const unsigned int*)&mask_s[m][c*4+3])[half];
            qw0 = ((const unsigned int*)&mask_s[m+16][c*4+0])[half];
            qw1 = ((const unsigned int*)&mask_s[m+16][c*4+1])[half];
            qw2 = ((const unsigned int*)&mask_s[m+16][c*4+2])[half];
            qw3 = ((const unsigned int*)&mask_s[m+16][c*4+3])[half];
#pragma unroll
            for (int ks = 0; ks < 2; ++ks) {
                f16x8 bb0 = ks ? cbB0 : cbA0;
                f16x8 bb1 = ks ? cbB1 : cbA1;
                float wv8[8];
                if (ks == 0) { *(float4*)&wv8[0] = cu0; *(float4*)&wv8[4] = cu1; }
                else         { *(float4*)&wv8[0] = cv0; *(float4*)&wv8[4] = cv1; }
                float Bj[8], Bp8[8];
                {
                    const float* Bb = &Btab[h][0][t * 64 + ks * 32 + quad * 8];
                    const float* Pb = &Btab[h][1][t * 64 + ks * 32 + quad * 8];
                    *(float4*)&Bj[0]  = *(const float4*)Bb;
                    *(float4*)&Bj[4]  = *(const float4*)(Bb + 4);
                    *(float4*)&Bp8[0] = *(const float4*)Pb;
                    *(float4*)&Bp8[4] = *(const float4*)(Pb + 4);
                }
                const int sh = ((16 * q4 + 8 * ks) & 31) + 2 * quad;
                const unsigned int gp0 = (pw0 >> sh) & 3u;
                const unsigned int gp1 = (pw1 >> sh) & 3u;
                const unsigned int gp2 = (pw2 >> sh) & 3u;
                const unsigned int gp3 = (pw3 >> sh) & 3u;
                const unsigned int gq0 = (qw0 >> sh) & 3u;
                const unsigned int gq1 = (qw1 >> sh) & 3u;
                const unsigned int gq2 = (qw2 >> sh) & 3u;
                const unsigned int gq3 = (qw3 >> sh) & 3u;
                f16x8 af0, af1;
#pragma unroll
                for (int qq = 0; qq < 4; ++qq) {
                    float r0p[2], r1p[2];
#pragma unroll
                    for (int cc = 0; cc < 2; ++cc) {
                        const int jj = qq * 2 + cc;
                        const unsigned int bsel = 1u << (jj >> 2);
                        const unsigned int gp = (jj&3)==0?gp0:(jj&3)==1?gp1:(jj&3)==2?gp2:gp3;
                        const unsigned int gq = (jj&3)==0?gq0:(jj&3)==1?gq1:(jj&3)==2?gq2:gq3;
                        const float w2v = wv8[jj];
                        float v0s = (w2v > th0) ? Fp0 * Bj[jj] : Fn0 * Bp8[jj];
                        r0p[cc] = ((gp & bsel) == 0u || w2v == th0) ? 0.f : v0s;
                        float v1s = (w2v > th1) ? Fp1 * Bj[jj] : Fn1 * Bp8[jj];
                        r1p[cc] = ((gq & bsel) == 0u || w2v == th1) ? 0.f : v1s;
                    }
                    auto pr0 = __builtin_amdgcn_cvt_pkrtz(r0p[0], r0p[1]);
                    af0[qq*2] = (_Float16)pr0[0]; af0[qq*2+1] = (_Float16)pr0[1];
                    auto pr1 = __builtin_amdgcn_cvt_pkrtz(r1p[0], r1p[1]);
                    af1[qq*2] = (_Float16)pr1[0]; af1[qq*2+1] = (_Float16)pr1[1];
                }
                a00 = __builtin_amdgcn_mfma_f32_16x16x32_f16(af0, bb0, a00, 0, 0, 0);
                a01 = __builtin_amdgcn_mfma_f32_16x16x32_f16(af0, bb1, a01, 0, 0, 0);
                a02 = __builtin_amdgcn_mfma_f32_16x16x32_f16(af0, ones, a02, 0, 0, 0);
                a10 = __builtin_amdgcn_mfma_f32_16x16x32_f16(af1, bb0, a10, 0, 0, 0);
                a11 = __builtin_amdgcn_mfma_f32_16x16x32_f16(af1, bb1, a11, 0, 0, 0);
                a12 = __builtin_amdgcn_mfma_f32_16x16x32_f16(af1, ones, a12, 0, 0, 0);
            }
            // ---- rotate prefetched tile into current ----
            cbA0 = nbA0; cbB0 = nbB0; cbA1 = nbA1; cbB1 = nbB1;
            cu0 = nu0; cu1 = nu1; cv0 = nv0; cv1 = nv1;
        }
    }
    float* xp = x2p + (((size_t)split * B_ + b) * N_ + i0) * D_ + h * HID_;
#pragma unroll
    for (int reg = 0; reg < 4; ++reg) {
        const int row = quad * 4 + reg;
        xp[(size_t)row * D_ + m] = a00[reg];
        xp[(size_t)row * D_ + 16 + m] = a01[reg];
        xp[(size_t)(row + 16) * D_ + m] = a10[reg];
        xp[(size_t)(row + 16) * D_ + 16 + m] = a11[reg];
    }
    if (m == 0) {
        float* lp = l1p + (((size_t)split * B_ + b) * N_ + i0) * H_ + h;
#pragma unroll
        for (int reg = 0; reg < 4; ++reg) {
            lp[(size_t)(quad * 4 + reg) * H_] = a02[reg];
            lp[(size_t)(quad * 4 + reg + 16) * H_] = a12[reg];
        }
    }
}

// ---------- merged layer-2 projection (unchanged)
__global__ __launch_bounds__(256) void proj2_kernel(
    const float* __restrict__ x2p, const float* __restrict__ l1p,
    const float* __restrict__ Wl, const float* __restrict__ a_last,
    float* __restrict__ wh1b, float* __restrict__ wh2b,
    float* __restrict__ cmax2, unsigned short* __restrict__ whT2t)
{
    __shared__ float Ws[D_ * EN_];
    __shared__ float xs[16][D_];
    __shared__ float as_[2 * EN_];
    __shared__ unsigned short ts[EN_][16];
    __shared__ float rmax[16];
    const int b = blockIdx.y, i0 = blockIdx.x * 16, tid = threadIdx.x;
    for (int idx = tid * 4; idx < D_ * EN_; idx += 1024)
        *(float4*)&Ws[idx] = *(const float4*)(Wl + idx);
    if (tid < 2 * EN_) as_[tid] = a_last[tid];
    for (int idx = tid * 4; idx < 16 * D_; idx += 1024) {
        const int r = idx >> 7, hd = idx & 127, h = hd >> 5;
        float4 v = {0.f, 0.f, 0.f, 0.f};
        float l = 0.f;
#pragma unroll
        for (int s = 0; s < S1_; ++s) {
            const size_t gi = ((size_t)s * B_ + b) * N_ + i0 + r;
            float4 p = *(const float4*)(x2p + gi * D_ + hd);
            v.x += p.x; v.y += p.y; v.z += p.z; v.w += p.w;
            l += l1p[gi * H_ + h];
        }
        float linv = 1.f / fmaxf(l, 1e-30f);
        float o0 = v.x * linv, o1 = v.y * linv, o2 = v.z * linv, o3 = v.w * linv;
        xs[r][hd]     = o0 > 0.f ? o0 : expm1f(o0);
        xs[r][hd + 1] = o1 > 0.f ? o1 : expm1f(o1);
        xs[r][hd + 2] = o2 > 0.f ? o2 : expm1f(o2);
        xs[r][hd + 3] = o3 > 0.f ? o3 : expm1f(o3);
    }
    __syncthreads();
    const int r = tid >> 4, e = tid & 15;
    float acc = 0.f;
#pragma unroll 8
    for (int k = 0; k < D_; ++k) acc += xs[r][k] * Ws[k * EN_ + e];
    ts[e][r] = f2h(acc);
    float d1 = acc * as_[e], d2 = acc * as_[EN_ + e];
#pragma unroll
    for (int off = 8; off; off >>= 1) {
        d1 += __shfl_xor(d1, off);
        d2 += __shfl_xor(d2, off);
    }
    d1 *= LOG2E_; d2 *= LOG2E_;
    if (e == 0) {
        wh1b[(size_t)b * N_ + i0 + r] = d1;
        wh2b[(size_t)b * N_ + i0 + r] = d2;
        rmax[r] = d2;
    }
    __syncthreads();
    if (tid < EN_) {
        unsigned short* dst = whT2t + (size_t)b * 65536
                            + (i0 >> 6) * 1024 + tid * 64 + (i0 & 63);
        *(u16x8*)dst = *(u16x8*)&ts[tid][0];
        *(u16x8*)(dst + 8) = *(u16x8*)&ts[tid][8];
    }
    if (tid == 0) {
        float mx = rmax[0];
#pragma unroll
        for (int k = 1; k < 16; ++k) mx = fmaxf(mx, rmax[k]);
        cmax2[(size_t)b * 256 + blockIdx.x] = mx;
    }
}

// ---------- layer-2 fused MFMA attention (same one-tile-ahead prefetch)
__global__ __launch_bounds__(256) void attn2_kernel(
    const unsigned long long* __restrict__ mask, const unsigned short* __restrict__ whT2,
    const float* __restrict__ wh1b, const float* __restrict__ wh2b,
    const float* __restrict__ cmax2,
    float* __restrict__ outp, float* __restrict__ outlp)
{
    __shared__ unsigned long long mask_s[32][17];
    __shared__ float accred[4][32][17];
    __shared__ float lred[4][32];
    __shared__ float Btab2[2][1024];       // 8 KB
    const int b = blockIdx.z, split = blockIdx.y, i0 = blockIdx.x * 32;
    const int tid = threadIdx.x, lane = tid & 63, wv = tid >> 6;
    const int m = lane & 15, quad = lane >> 4;
    {
        const int r = tid >> 3, w = (tid & 7) * 2;
        ulonglong2 mw = *(const ulonglong2*)(mask + ((size_t)b * N_ + i0 + r) * 64
                                             + split * 16 + w);
        mask_s[r][w] = mw.x; mask_s[r][w + 1] = mw.y;
    }
    const float* cm = cmax2 + (size_t)b * 256;
    float4 c0 = *(const float4*)(cm + lane * 4);
    float Mh = fmaxf(fmaxf(c0.x, c0.y), fmaxf(c0.z, c0.w));
#pragma unroll
    for (int off = 32; off; off >>= 1) Mh = fmaxf(Mh, __shfl_xor(Mh, off));
    // fill shared (B, B') table: 4 j's per thread
    {
        float4 v = *(const float4*)(wh2b + (size_t)b * N_ + split * 1024 + tid * 4);
        float4 eb, ep;
        eb.x = __builtin_amdgcn_exp2f(v.x - Mh);
        eb.y = __builtin_amdgcn_exp2f(v.y - Mh);
        eb.z = __builtin_amdgcn_exp2f(v.z - Mh);
        eb.w = __builtin_amdgcn_exp2f(v.w - Mh);
        ep.x = __builtin_amdgcn_exp2f(ALPHA_ * (v.x - Mh));
        ep.y = __builtin_amdgcn_exp2f(ALPHA_ * (v.y - Mh));
        ep.z = __builtin_amdgcn_exp2f(ALPHA_ * (v.z - Mh));
        ep.w = __builtin_amdgcn_exp2f(ALPHA_ * (v.w - Mh));
        *(float4*)&Btab2[0][tid * 4] = eb;
        *(float4*)&Btab2[1][tid * 4] = ep;
    }
    const float w1r0 = wh1b[(size_t)b * N_ + i0 + m];
    const float w1r1 = wh1b[(size_t)b * N_ + i0 + 16 + m];
    const float sb0 = w1r0 + Mh, sb1 = w1r1 + Mh;
    const float mr0 = fmaxf(sb0, ALPHA_ * sb0);
    const float mr1 = fmaxf(sb1, ALPHA_ * sb1);
    const float th0 = -w1r0, th1 = -w1r1;
    const float Fp0 = __builtin_amdgcn_exp2f(sb0 - mr0);
    const float Fn0 = __builtin_amdgcn_exp2f(ALPHA_ * sb0 - mr0);
    const float Fp1 = __builtin_amdgcn_exp2f(sb1 - mr1);
    const float Fn1 = __builtin_amdgcn_exp2f(ALPHA_ * sb1 - mr1);
    const unsigned short* wTb = whT2 + (size_t)b * 65536
                              + (size_t)(split * 16 + wv * 4) * 1024 + m * 64 + quad * 8;
    const float* wvb = wh2b + (size_t)b * N_ + split * 1024 + wv * 256 + quad * 8;
    f32x4 a0 = {0.f,0.f,0.f,0.f}, a1 = {0.f,0.f,0.f,0.f};
    f32x4 l0 = {0.f,0.f,0.f,0.f}, l1 = {0.f,0.f,0.f,0.f};
    f16x8 ones;
#pragma unroll
    for (int q = 0; q < 8; ++q) ones[q] = (_Float16)1.0f;
    // prologue loads (overlap barrier)
    f16x8 cb0 = *(const f16x8*)(wTb);
    f16x8 cb1 = *(const f16x8*)(wTb + 32);
    float4 cu0 = *(const float4*)(wvb);
    float4 cu1 = *(const float4*)(wvb + 4);
    float4 cv0 = *(const float4*)(wvb + 32);
    float4 cv1 = *(const float4*)(wvb + 36);
    __syncthreads();
#pragma unroll
    for (int q4 = 0; q4 < 4; ++q4) {
        const int tn = (q4 < 3) ? q4 + 1 : 3;
        const unsigned short* bpn = wTb + (size_t)tn * 1024;
        const float* nwn = wvb + tn * 64;
        f16x8 nb0 = *(const f16x8*)(bpn);
        f16x8 nb1 = *(const f16x8*)(bpn + 32);
        float4 nu0 = *(const float4*)(nwn);
        float4 nu1 = *(const float4*)(nwn + 4);
        float4 nv0 = *(const float4*)(nwn + 32);
        float4 nv1 = *(const float4*)(nwn + 36);
        const int half = q4 >> 1;
        unsigned int pw0, pw1, pw2, pw3, qw0, qw1, qw2, qw3;
        pw0 = ((const unsigned int*)&mask_s[m][wv*4+0])[half];
        pw1 = ((const unsigned int*)&mask_s[m][wv*4+1])[half];
        pw2 = ((const unsigned int*)&mask_s[m][wv*4+2])[half];
        pw3 = ((const unsigned int*)&mask_s[m][wv*4+3])[half];
        qw0 = ((const unsigned int*)&mask_s[m+16][wv*4+0])[half];
        qw1 = ((const unsigned int*)&mask_s[m+16][wv*4+1])[half];
        qw2 = ((const unsigned int*)&mask_s[m+16][wv*4+2])[half];
        qw3 = ((const unsigned int*)&mask_s[m+16][wv*4+3])[half];
#pragma unroll
        for (int ks = 0; ks < 2; ++ks) {
            f16x8 bb = ks ? cb1 : cb0;
            float wv8[8];
            if (ks == 0) { *(float4*)&wv8[0] = cu0; *(float4*)&wv8[4] = cu1; }
            else         { *(float4*)&wv8[0] = cv0; *(float4*)&wv8[4] = cv1; }
            float Bj[8], Bp8[8];
            {
                const float* Bb = &Btab2[0][wv * 256 + q4 * 64 + ks * 32 + quad * 8];
                const float* Pb = &Btab2[1][wv * 256 + q4 * 64 + ks * 32 + quad * 8];
                *(float4*)&Bj[0]  = *(const float4*)Bb;
                *(float4*)&Bj[4]  = *(const float4*)(Bb + 4);
                *(float4*)&Bp8[0] = *(const float4*)Pb;
                *(float4*)&Bp8[4] = *(const float4*)(Pb + 4);
            }
            const int sh = ((16 * q4 + 8 * ks) & 31) + 2 * quad;
            const unsigned int gp0 = (pw0 >> sh) & 3u;
            const unsigned int gp1 = (pw1 >> sh) & 3u;
            const unsigned int gp2 = (pw2 >> sh) & 3u;
            const unsigned int gp3 = (pw3 >> sh) & 3u;
            const unsigned int gq0 = (qw0 >> sh) & 3u;
            const unsigned int gq1 = (qw1 >> sh) & 3u;
            const unsigned int gq2 = (qw2 >> sh) & 3u;
            const unsigned int gq3 = (qw3 >> sh) & 3u;
            f16x8 af0, af1;
#pragma unroll
            for (int qq = 0; qq < 4; ++qq) {
                float r0p[2], r1p[2];
#pragma unroll
                for (int cc = 0; cc < 2; ++cc) {
                    const int jj = qq * 2 + cc;
                    const unsigned int bsel = 1u << (jj >> 2);
                    const unsigned int gp = (jj&3)==0?gp0:(jj&3)==1?gp1:(jj&3)==2?gp2:gp3;
                    const unsigned int gq = (jj&3)==0?gq0:(jj&3)==1?gq1:(jj&3)==2?gq2:gq3;
                    const float w2v = wv8[jj];
                    float v0s = (w2v > th0) ? Fp0 * Bj[jj] : Fn0 * Bp8[jj];
                    r0p[cc] = ((gp & bsel) == 0u || w2v == th0) ? 0.f : v0s;
                    float v1s = (w2v > th1) ? Fp1 * Bj[jj] : Fn1 * Bp8[jj];
                    r1p[cc] = ((gq & bsel) == 0u || w2v == th1) ? 0.f : v1s;
                }
                auto pr0 = __builtin_amdgcn_cvt_pkrtz(r0p[0], r0p[1]);
                af0[qq*2] = (_Float16)pr0[0]; af0[qq*2+1] = (_Float16)pr0[1];
                auto pr1 = __builtin_amdgcn_cvt_pkrtz(r1p[0], r1p[1]);
                af1[qq*2] = (_Float16)pr1[0]; af1[qq*2+1] = (_Float16)pr1[1];
            }
            a0 = __builtin_amdgcn_mfma_f32_16x16x32_f16(af0, bb, a0, 0, 0, 0);
            l0 = __builtin_amdgcn_mfma_f32_16x16x32_f16(af0, ones, l0, 0, 0, 0);
            a1 = __builtin_amdgcn_mfma_f32_16x16x32_f16(af1, bb, a1, 0, 0, 0);
            l1 = __builtin_amdgcn_mfma_f32_16x16x32_f16(af1, ones, l1, 0, 0, 0);
        }
        cb0 = nb0; cb1 = nb1;
        cu0 = nu0; cu1 = nu1; cv0 = nv0; cv1 = nv1;
    }
#pragma unroll
    for (int reg = 0; reg < 4; ++reg) {
        accred[wv][quad * 4 + reg][m] = a0[reg];
        accred[wv][quad * 4 + reg + 16][m] = a1[reg];
    }
    if (m == 0) {
#pragma unroll
        for (int reg = 0; reg < 4; ++reg) {
            lred[wv][quad * 4 + reg] = l0[reg];
            lred[wv][quad * 4 + reg + 16] = l1[reg];
        }
    }
    __syncthreads();
    const int row = tid >> 4, col = tid & 15;
    float s0 = accred[0][row][col] + accred[1][row][col]
             + accred[2][row][col] + accred[3][row][col];
    float s1 = accred[0][row + 16][col] + accred[1][row + 16][col]
             + accred[2][row + 16][col] + accred[3][row + 16][col];
    float* op = outp + (((size_t)split * B_ + b) * N_ + i0) * EN_;
    op[(size_t)row * EN_ + col] = s0;
    op[(size_t)(row + 16) * EN_ + col] = s1;
    if (tid < 32) {
        float l = lred[0][tid] + lred[1][tid] + lred[2][tid] + lred[3][tid];
        outlp[((size_t)split * B_ + b) * N_ + i0 + tid] = l;
    }
}

// ---------- final: sum split partials, divide, ELU
__global__ __launch_bounds__(256) void finalize2_kernel(
    const float* __restrict__ outp, const float* __restrict__ outlp,
    float* __restrict__ out)
{
    const int id = blockIdx.x * 256 + threadIdx.x;      // B*N*EN
    const int gi = id >> 4;
    float num = 0.f, l = 0.f;
#pragma unroll
    for (int s = 0; s < S2_; ++s) {
        num += outp[(size_t)s * B_ * N_ * EN_ + id];
        l   += outlp[(size_t)s * B_ * N_ + gi];
    }
    float v = num / fmaxf(l, 1e-30f);
    out[id] = v > 0.f ? v : expm1f(v);
}

extern "C" void kernel_launch(void* const* d_in, const int* in_sizes, int n_in,
                              void* d_out, int out_size, void* d_ws, size_t ws_size,
                              hipStream_t stream)
{
    const float* fea = (const float*)d_in[0];
    const float* adj = (const float*)d_in[1];
    const float* Wh  = (const float*)d_in[2];
    const float* ah  = (const float*)d_in[3];
    const float* Wl  = (const float*)d_in[4];
    const float* al  = (const float*)d_in[5];

    float* p = (float*)d_ws;
    float* wh1   = p;  p += (size_t)B_ * H_ * N_;            // 32768
    float* wh2   = p;  p += (size_t)B_ * H_ * N_;            // 32768
    float* wh1b  = p;  p += (size_t)B_ * N_;                 // 8192
    float* wh2b  = p;  p += (size_t)B_ * N_;                 // 8192
    float* cmax1 = p;  p += (size_t)B_ * H_ * 128;           // 1024
    float* cmax2 = p;  p += (size_t)B_ * 256;                // 512
    float* l1p   = p;  p += (size_t)S1_ * B_ * N_ * H_;      // 131072
    float* x2p   = p;  p += (size_t)S1_ * B_ * N_ * D_;      // 4194304
    float* outp  = p;  p += (size_t)S2_ * B_ * N_ * EN_;     // 524288
    float* outlp = p;  p += (size_t)S2_ * B_ * N_;           // 32768
    unsigned long long* mask = (unsigned long long*)p;       // B*N*64 u64 = 4 MB
    unsigned short* whTt  = (unsigned short*)(mask + (size_t)B_ * N_ * 64);  // 2 MB
    unsigned short* whT2t = whTt + (size_t)B_ * H_ * 131072;                 // 256 KB

    prep_kernel<<<B_ * H_ * 128, 256, 0, stream>>>(fea, Wh, ah,
                                                   wh1, wh2, cmax1, whTt);
    attn1_kernel<<<dim3(N_ / 32, S1_, B_), 256, 0, stream>>>(adj, mask, whTt,
                                                             wh1, wh2, cmax1,
                                                             x2p, l1p);
    proj2_kernel<<<dim3(N_ / 16, B_), 256, 0, stream>>>(x2p, l1p, Wl, al,
                                                        wh1b, wh2b, cmax2, whT2t);
    attn2_kernel<<<dim3(N_ / 32, S2_, B_), 256, 0, stream>>>(mask, whT2t, wh1b, wh2b, cmax2,
                                                             outp, outlp);
    finalize2_kernel<<<(B_ * N_ * EN_) / 256, 256, 0, stream>>>(outp, outlp, (float*)d_out);
}

// Round 9
// 295.285 us; speedup vs baseline: 1.0080x; 1.0080x over previous
//
#include <hip/hip_runtime.h>
#include <hip/hip_bf16.h>
#include <stdint.h>

#define B_ 2
#define N_ 4096
#define D_ 128
#define H_ 4
#define HID_ 32
#define EN_ 16
#define ALPHA_ 0.2f
#define S1_ 4
#define S2_ 4
#define LOG2E_ 1.4426950408889634f

typedef __attribute__((ext_vector_type(8))) _Float16 f16x8;
typedef __attribute__((ext_vector_type(4))) float f32x4;
typedef __attribute__((ext_vector_type(8))) unsigned short u16x8;

__device__ __forceinline__ unsigned short f2h(float v) {
    _Float16 h = (_Float16)v;
    return *(unsigned short*)&h;
}
__device__ __forceinline__ _Float16 u2h(unsigned short u) { return *(_Float16*)&u; }
__device__ __forceinline__ unsigned short h2u(_Float16 h) { return *(unsigned short*)&h; }
__device__ __forceinline__ unsigned int pk2(float lo, float hi) {
    auto pr = __builtin_amdgcn_cvt_pkrtz(lo, hi);
    return *(unsigned int*)&pr;
}

// ---------- fused prep (R5 structure): blocks [0,2048) = adj->bitmask;
// [2048,3072) = layer-1 proj. BW-bound mask stream across 2048 blocks.
__global__ __launch_bounds__(256) void prep_kernel(
    const float* __restrict__ adj, unsigned long long* __restrict__ mask,
    const float* __restrict__ fea, const float* __restrict__ Wh,
    const float* __restrict__ a_heads,
    float* __restrict__ wh1, float* __restrict__ wh2,
    float* __restrict__ cmax1, unsigned short* __restrict__ whTt)
{
    __shared__ float xs[32][132];          // 16.9 KB
    __shared__ float WT[32][132];          // 16.9 KB
    __shared__ float Wa[2][128];
    __shared__ float as_[2 * HID_];
    __shared__ unsigned short ts[32][32];  // [d][r]
    __shared__ float rmax[32];
    const int tid = threadIdx.x;

    if (blockIdx.x < 2048) {               // ---- mask part ----
        const int b = blockIdx.x >> 10, ib = blockIdx.x & 1023;
        const int i = ib * 4 + (tid >> 6);
        const int lane = tid & 63;
        const float* ar = adj + ((size_t)b * N_ + i) * N_;
        unsigned long long* mrow = mask + ((size_t)b * N_ + i) * 64;
#pragma unroll 4
        for (int c = 0; c < 16; ++c) {
            float4 v = *(const float4*)(ar + c * 256 + lane * 4);
            unsigned long long b0 = __ballot(v.x != 0.f);
            unsigned long long b1 = __ballot(v.y != 0.f);
            unsigned long long b2 = __ballot(v.z != 0.f);
            unsigned long long b3 = __ballot(v.w != 0.f);
            if (lane == 0) {
                ulonglong2 w01 = {b0, b1}, w23 = {b2, b3};
                *(ulonglong2*)(mrow + c * 4) = w01;
                *(ulonglong2*)(mrow + c * 4 + 2) = w23;
            }
        }
        return;
    }
    // ---- proj1 part: 32 rows x 32 cols, one head ----
    const int l0 = blockIdx.x - 2048;
    const int ib = l0 & 127, h = (l0 >> 7) & 3, b = l0 >> 9;
    const int i0 = ib * 32;
    const float* Wp = Wh + (size_t)h * D_ * HID_;
    for (int l = tid; l < 1024; l += 256) {          // W[k][d] -> WT[d][k]
        float4 w4 = *(const float4*)(Wp + l * 4);
        int k = l >> 3, d = (l & 7) * 4;
        WT[d][k] = w4.x; WT[d + 1][k] = w4.y; WT[d + 2][k] = w4.z; WT[d + 3][k] = w4.w;
    }
    if (tid < 2 * HID_) as_[tid] = a_heads[h * 2 * HID_ + tid];
    const float* xp = fea + ((size_t)b * N_ + i0) * D_;
    for (int l = tid; l < 1024; l += 256) {
        int r = l >> 5, k4 = (l & 31) * 4;
        *(float4*)&xs[r][k4] = *(const float4*)(xp + r * D_ + k4);
    }
    __syncthreads();
    // Wa[j][k] = sum_d W[k][d]*a[j*HID+d]
    {
        const int k = tid & 127, j = tid >> 7;
        const float* wr = Wp + k * HID_;
        const float* aw = &as_[j * HID_];
        float s = 0.f;
#pragma unroll
        for (int d = 0; d < HID_; d += 4) {
            float4 w4 = *(const float4*)(wr + d);
            s += w4.x * aw[d] + w4.y * aw[d + 1] + w4.z * aw[d + 2] + w4.w * aw[d + 3];
        }
        Wa[j][k] = s;
    }
    const int c = tid & 15, rg = (tid >> 4) * 2;     // rows rg,rg+1; cols c,c+16
    float a0[2] = {0.f, 0.f}, a1[2] = {0.f, 0.f};
#pragma unroll 8
    for (int k = 0; k < D_; k += 4) {
        float4 w0 = *(float4*)&WT[c][k];
        float4 w1 = *(float4*)&WT[c + 16][k];
#pragma unroll
        for (int i = 0; i < 2; ++i) {
            float4 x4 = *(float4*)&xs[rg + i][k];
            a0[i] += x4.x * w0.x + x4.y * w0.y + x4.z * w0.z + x4.w * w0.w;
            a1[i] += x4.x * w1.x + x4.y * w1.y + x4.z * w1.z + x4.w * w1.w;
        }
    }
#pragma unroll
    for (int i = 0; i < 2; ++i) {
        ts[c][rg + i] = f2h(a0[i]);
        ts[c + 16][rg + i] = f2h(a1[i]);
    }
    __syncthreads();                                 // Wa + ts ready
    {
        const int row = tid >> 3, q = tid & 7;       // 32 rows x 8 threads
        float d1 = 0.f, d2 = 0.f;
#pragma unroll
        for (int k = q * 16; k < q * 16 + 16; k += 4) {
            float4 x4 = *(float4*)&xs[row][k];
            float4 u = *(float4*)&Wa[0][k];
            float4 v = *(float4*)&Wa[1][k];
            d1 += x4.x * u.x + x4.y * u.y + x4.z * u.z + x4.w * u.w;
            d2 += x4.x * v.x + x4.y * v.y + x4.z * v.z + x4.w * v.w;
        }
        d1 += __shfl_xor(d1, 1); d1 += __shfl_xor(d1, 2); d1 += __shfl_xor(d1, 4);
        d2 += __shfl_xor(d2, 1); d2 += __shfl_xor(d2, 2); d2 += __shfl_xor(d2, 4);
        if (q == 0) {
            const size_t o = (size_t)(b * H_ + h) * N_ + i0 + row;
            wh1[o] = d1 * LOG2E_;
            wh2[o] = d2 * LOG2E_;
            rmax[row] = d2 * LOG2E_;
        }
    }
    __syncthreads();
    if (tid < 128) {                                 // whT tile out (1024 halfwords)
        const int d = tid >> 2, part = (tid & 3) * 8;
        unsigned short* dst = whTt + ((size_t)(b * H_ + h) * 64 + (i0 >> 6)) * 2048
                            + d * 64 + (i0 & 63) + part;
        *(u16x8*)dst = *(u16x8*)&ts[d][part];
    }
    if (tid < 32) {
        float mx = rmax[tid];
#pragma unroll
        for (int off = 16; off; off >>= 1) mx = fmaxf(mx, __shfl_xor(mx, off));
        if (tid == 0) cmax1[(size_t)(b * H_ + h) * 128 + ib] = mx;
    }
}

// ---------- layer-1 fused MFMA attention.
// R9 (counters-driven): attn was latency-bound at ~43% occupancy (R7: VALU 32%,
// MFMA 4%, HBM 11%); R8 showed per-wave prefetch works but VGPR cost halves
// occupancy. Fix occupancy via LDS instead: Btab packed as u32 = (f16 B | f16
// B' << 16) -> 16KB (was 32KB). LDS 20.7KB -> 7 blocks/CU (87% occ, was 4/43%).
// Inner loop: select f16 half by sign, v_mul_f16 with pre-converted f16 row
// factor, write af directly (drops cvt_pkrtz + one f32 mul per score).
__global__ __launch_bounds__(256) void attn1_kernel(
    const unsigned long long* __restrict__ mask, const unsigned short* __restrict__ whT,
    const float* __restrict__ wh1, const float* __restrict__ wh2,
    const float* __restrict__ cmax1,
    float* __restrict__ x2p, float* __restrict__ l1p)
{
    __shared__ unsigned long long mask_s[32][17];
    __shared__ unsigned int Btab[H_][1024];   // 16 KB packed (B, B') f16 pairs
    const int b = blockIdx.z, split = blockIdx.y, i0 = blockIdx.x * 32;
    const int tid = threadIdx.x, lane = tid & 63, h = tid >> 6;
    const int m = lane & 15, quad = lane >> 4;
    {
        const int r = tid >> 3, w = (tid & 7) * 2;
        ulonglong2 mw = *(const ulonglong2*)(mask + ((size_t)b * N_ + i0 + r) * 64
                                             + split * 16 + w);
        mask_s[r][w] = mw.x; mask_s[r][w + 1] = mw.y;
    }
    const float* cm = cmax1 + (size_t)(b * H_ + h) * 128;
    float Mh = fmaxf(cm[lane], cm[lane + 64]);
#pragma unroll
    for (int off = 32; off; off >>= 1) Mh = fmaxf(Mh, __shfl_xor(Mh, off));
    const size_t bhN = (size_t)(b * H_ + h) * N_;
    // fill this head's packed (B, B') table: 1024 j's, 16 per lane
    const float* w2g = wh2 + bhN + split * 1024;
#pragma unroll
    for (int g = 0; g < 4; ++g) {
        float4 v = *(const float4*)(w2g + g * 256 + lane * 4);
        unsigned int q0 = pk2(__builtin_amdgcn_exp2f(v.x - Mh),
                              __builtin_amdgcn_exp2f(ALPHA_ * (v.x - Mh)));
        unsigned int q1 = pk2(__builtin_amdgcn_exp2f(v.y - Mh),
                              __builtin_amdgcn_exp2f(ALPHA_ * (v.y - Mh)));
        unsigned int q2 = pk2(__builtin_amdgcn_exp2f(v.z - Mh),
                              __builtin_amdgcn_exp2f(ALPHA_ * (v.z - Mh)));
        unsigned int q3 = pk2(__builtin_amdgcn_exp2f(v.w - Mh),
                              __builtin_amdgcn_exp2f(ALPHA_ * (v.w - Mh)));
        uint4 qq = {q0, q1, q2, q3};
        *(uint4*)&Btab[h][g * 256 + lane * 4] = qq;
    }
    const float w1r0 = wh1[bhN + i0 + m];
    const float w1r1 = wh1[bhN + i0 + 16 + m];
    const float sb0 = w1r0 + Mh, sb1 = w1r1 + Mh;
    const float mr0 = fmaxf(sb0, ALPHA_ * sb0);
    const float mr1 = fmaxf(sb1, ALPHA_ * sb1);
    const float th0 = -w1r0, th1 = -w1r1;
    const unsigned short Fp0u = h2u((_Float16)__builtin_amdgcn_exp2f(sb0 - mr0));
    const unsigned short Fn0u = h2u((_Float16)__builtin_amdgcn_exp2f(ALPHA_ * sb0 - mr0));
    const unsigned short Fp1u = h2u((_Float16)__builtin_amdgcn_exp2f(sb1 - mr1));
    const unsigned short Fn1u = h2u((_Float16)__builtin_amdgcn_exp2f(ALPHA_ * sb1 - mr1));
    const float* wvb = wh2 + bhN + split * 1024 + quad * 8;
    const unsigned short* bpb = whT + (size_t)(b * H_ + h) * 131072
                              + (size_t)split * 16 * 2048 + m * 64 + quad * 8;
    f32x4 a00 = {0.f,0.f,0.f,0.f}, a01 = {0.f,0.f,0.f,0.f}, a02 = {0.f,0.f,0.f,0.f};
    f32x4 a10 = {0.f,0.f,0.f,0.f}, a11 = {0.f,0.f,0.f,0.f}, a12 = {0.f,0.f,0.f,0.f};
    f16x8 ones;
#pragma unroll
    for (int q = 0; q < 8; ++q) ones[q] = (_Float16)1.0f;
    __syncthreads();

    for (int c = 0; c < 4; ++c) {
#pragma unroll
        for (int q4 = 0; q4 < 4; ++q4) {
            const int t = c * 4 + q4;
            const int half = q4 >> 1;                // dword half of the 64-bit word
            unsigned int pw0, pw1, pw2, pw3, qw0, qw1, qw2, qw3;
            pw0 = ((const unsigned int*)&mask_s[m][c*4+0])[half];
            pw1 = ((const unsigned int*)&mask_s[m][c*4+1])[half];
            pw2 = ((const unsigned int*)&mask_s[m][c*4+2])[half];
            pw3 = ((const unsigned int*)&mask_s[m][c*4+3])[half];
            qw0 = ((const unsigned int*)&mask_s[m+16][c*4+0])[half];
            qw1 = ((const unsigned int*)&mask_s[m+16][c*4+1])[half];
            qw2 = ((const unsigned int*)&mask_s[m+16][c*4+2])[half];
            qw3 = ((const unsigned int*)&mask_s[m+16][c*4+3])[half];
            const unsigned short* bp = bpb + (size_t)t * 2048;
            const float* nw = wvb + t * 64;
#pragma unroll
            for (int ks = 0; ks < 2; ++ks) {
                f16x8 bb0 = *(const f16x8*)(bp + ks * 32);
                f16x8 bb1 = *(const f16x8*)(bp + 1024 + ks * 32);
                float wv8[8];
                *(float4*)&wv8[0] = *(const float4*)(nw + ks * 32);
                *(float4*)&wv8[4] = *(const float4*)(nw + ks * 32 + 4);
                unsigned int Bpk[8];
                {
                    const unsigned int* Bb = &Btab[h][t * 64 + ks * 32 + quad * 8];
                    *(uint4*)&Bpk[0] = *(const uint4*)Bb;
                    *(uint4*)&Bpk[4] = *(const uint4*)(Bb + 4);
                }
                const int sh = ((16 * q4 + 8 * ks) & 31) + 2 * quad;
                const unsigned int gp0 = (pw0 >> sh) & 3u;
                const unsigned int gp1 = (pw1 >> sh) & 3u;
                const unsigned int gp2 = (pw2 >> sh) & 3u;
                const unsigned int gp3 = (pw3 >> sh) & 3u;
                const unsigned int gq0 = (qw0 >> sh) & 3u;
                const unsigned int gq1 = (qw1 >> sh) & 3u;
                const unsigned int gq2 = (qw2 >> sh) & 3u;
                const unsigned int gq3 = (qw3 >> sh) & 3u;
                f16x8 af0, af1;
#pragma unroll
                for (int jj = 0; jj < 8; ++jj) {
                    const unsigned int bsel = 1u << (jj >> 2);
                    const unsigned int gp = (jj&3)==0?gp0:(jj&3)==1?gp1:(jj&3)==2?gp2:gp3;
                    const unsigned int gq = (jj&3)==0?gq0:(jj&3)==1?gq1:(jj&3)==2?gq2:gq3;
                    const float w2v = wv8[jj];
                    const unsigned int pk = Bpk[jj];
                    const bool pos0 = (w2v > th0);
                    _Float16 bh0 = u2h((unsigned short)(pos0 ? (pk & 0xffffu) : (pk >> 16)));
                    _Float16 fh0 = u2h(pos0 ? Fp0u : Fn0u);
                    _Float16 p0 = bh0 * fh0;
                    af0[jj] = (((gp & bsel) == 0u) || (w2v == th0)) ? (_Float16)0.f : p0;
                    const bool pos1 = (w2v > th1);
                    _Float16 bh1 = u2h((unsigned short)(pos1 ? (pk & 0xffffu) : (pk >> 16)));
                    _Float16 fh1 = u2h(pos1 ? Fp1u : Fn1u);
                    _Float16 p1 = bh1 * fh1;
                    af1[jj] = (((gq & bsel) == 0u) || (w2v == th1)) ? (_Float16)0.f : p1;
                }
                a00 = __builtin_amdgcn_mfma_f32_16x16x32_f16(af0, bb0, a00, 0, 0, 0);
                a01 = __builtin_amdgcn_mfma_f32_16x16x32_f16(af0, bb1, a01, 0, 0, 0);
                a02 = __builtin_amdgcn_mfma_f32_16x16x32_f16(af0, ones, a02, 0, 0, 0);
                a10 = __builtin_amdgcn_mfma_f32_16x16x32_f16(af1, bb0, a10, 0, 0, 0);
                a11 = __builtin_amdgcn_mfma_f32_16x16x32_f16(af1, bb1, a11, 0, 0, 0);
                a12 = __builtin_amdgcn_mfma_f32_16x16x32_f16(af1, ones, a12, 0, 0, 0);
            }
        }
    }
    float* xp = x2p + (((size_t)split * B_ + b) * N_ + i0) * D_ + h * HID_;
#pragma unroll
    for (int reg = 0; reg < 4; ++reg) {
        const int row = quad * 4 + reg;
        xp[(size_t)row * D_ + m] = a00[reg];
        xp[(size_t)row * D_ + 16 + m] = a01[reg];
        xp[(size_t)(row + 16) * D_ + m] = a10[reg];
        xp[(size_t)(row + 16) * D_ + 16 + m] = a11[reg];
    }
    if (m == 0) {
        float* lp = l1p + (((size_t)split * B_ + b) * N_ + i0) * H_ + h;
#pragma unroll
        for (int reg = 0; reg < 4; ++reg) {
            lp[(size_t)(quad * 4 + reg) * H_] = a02[reg];
            lp[(size_t)(quad * 4 + reg + 16) * H_] = a12[reg];
        }
    }
}

// ---------- merged layer-2 projection (unchanged)
__global__ __launch_bounds__(256) void proj2_kernel(
    const float* __restrict__ x2p, const float* __restrict__ l1p,
    const float* __restrict__ Wl, const float* __restrict__ a_last,
    float* __restrict__ wh1b, float* __restrict__ wh2b,
    float* __restrict__ cmax2, unsigned short* __restrict__ whT2t)
{
    __shared__ float Ws[D_ * EN_];
    __shared__ float xs[16][D_];
    __shared__ float as_[2 * EN_];
    __shared__ unsigned short ts[EN_][16];
    __shared__ float rmax[16];
    const int b = blockIdx.y, i0 = blockIdx.x * 16, tid = threadIdx.x;
    for (int idx = tid * 4; idx < D_ * EN_; idx += 1024)
        *(float4*)&Ws[idx] = *(const float4*)(Wl + idx);
    if (tid < 2 * EN_) as_[tid] = a_last[tid];
    for (int idx = tid * 4; idx < 16 * D_; idx += 1024) {
        const int r = idx >> 7, hd = idx & 127, h = hd >> 5;
        float4 v = {0.f, 0.f, 0.f, 0.f};
        float l = 0.f;
#pragma unroll
        for (int s = 0; s < S1_; ++s) {
            const size_t gi = ((size_t)s * B_ + b) * N_ + i0 + r;
            float4 p = *(const float4*)(x2p + gi * D_ + hd);
            v.x += p.x; v.y += p.y; v.z += p.z; v.w += p.w;
            l += l1p[gi * H_ + h];
        }
        float linv = 1.f / fmaxf(l, 1e-30f);
        float o0 = v.x * linv, o1 = v.y * linv, o2 = v.z * linv, o3 = v.w * linv;
        xs[r][hd]     = o0 > 0.f ? o0 : expm1f(o0);
        xs[r][hd + 1] = o1 > 0.f ? o1 : expm1f(o1);
        xs[r][hd + 2] = o2 > 0.f ? o2 : expm1f(o2);
        xs[r][hd + 3] = o3 > 0.f ? o3 : expm1f(o3);
    }
    __syncthreads();
    const int r = tid >> 4, e = tid & 15;
    float acc = 0.f;
#pragma unroll 8
    for (int k = 0; k < D_; ++k) acc += xs[r][k] * Ws[k * EN_ + e];
    ts[e][r] = f2h(acc);
    float d1 = acc * as_[e], d2 = acc * as_[EN_ + e];
#pragma unroll
    for (int off = 8; off; off >>= 1) {
        d1 += __shfl_xor(d1, off);
        d2 += __shfl_xor(d2, off);
    }
    d1 *= LOG2E_; d2 *= LOG2E_;
    if (e == 0) {
        wh1b[(size_t)b * N_ + i0 + r] = d1;
        wh2b[(size_t)b * N_ + i0 + r] = d2;
        rmax[r] = d2;
    }
    __syncthreads();
    if (tid < EN_) {
        unsigned short* dst = whT2t + (size_t)b * 65536
                            + (i0 >> 6) * 1024 + tid * 64 + (i0 & 63);
        *(u16x8*)dst = *(u16x8*)&ts[tid][0];
        *(u16x8*)(dst + 8) = *(u16x8*)&ts[tid][8];
    }
    if (tid == 0) {
        float mx = rmax[0];
#pragma unroll
        for (int k = 1; k < 16; ++k) mx = fmaxf(mx, rmax[k]);
        cmax2[(size_t)b * 256 + blockIdx.x] = mx;
    }
}

// ---------- layer-2 fused MFMA attention: same packed-f16 Btab (4 KB).
// LDS 17.7KB -> 8 blocks/CU (VGPR-capped) = 100% occupancy.
__global__ __launch_bounds__(256) void attn2_kernel(
    const unsigned long long* __restrict__ mask, const unsigned short* __restrict__ whT2,
    const float* __restrict__ wh1b, const float* __restrict__ wh2b,
    const float* __restrict__ cmax2,
    float* __restrict__ outp, float* __restrict__ outlp)
{
    __shared__ unsigned long long mask_s[32][17];
    __shared__ float accred[4][32][17];
    __shared__ float lred[4][32];
    __shared__ unsigned int Btab2[1024];   // 4 KB packed
    const int b = blockIdx.z, split = blockIdx.y, i0 = blockIdx.x * 32;
    const int tid = threadIdx.x, lane = tid & 63, wv = tid >> 6;
    const int m = lane & 15, quad = lane >> 4;
    {
        const int r = tid >> 3, w = (tid & 7) * 2;
        ulonglong2 mw = *(const ulonglong2*)(mask + ((size_t)b * N_ + i0 + r) * 64
                                             + split * 16 + w);
        mask_s[r][w] = mw.x; mask_s[r][w + 1] = mw.y;
    }
    const float* cm = cmax2 + (size_t)b * 256;
    float4 c0 = *(const float4*)(cm + lane * 4);
    float Mh = fmaxf(fmaxf(c0.x, c0.y), fmaxf(c0.z, c0.w));
#pragma unroll
    for (int off = 32; off; off >>= 1) Mh = fmaxf(Mh, __shfl_xor(Mh, off));
    // fill shared packed (B, B') table: 4 j's per thread
    {
        float4 v = *(const float4*)(wh2b + (size_t)b * N_ + split * 1024 + tid * 4);
        unsigned int q0 = pk2(__builtin_amdgcn_exp2f(v.x - Mh),
                              __builtin_amdgcn_exp2f(ALPHA_ * (v.x - Mh)));
        unsigned int q1 = pk2(__builtin_amdgcn_exp2f(v.y - Mh),
                              __builtin_amdgcn_exp2f(ALPHA_ * (v.y - Mh)));
        unsigned int q2 = pk2(__builtin_amdgcn_exp2f(v.z - Mh),
                              __builtin_amdgcn_exp2f(ALPHA_ * (v.z - Mh)));
        unsigned int q3 = pk2(__builtin_amdgcn_exp2f(v.w - Mh),
                              __builtin_amdgcn_exp2f(ALPHA_ * (v.w - Mh)));
        uint4 qq = {q0, q1, q2, q3};
        *(uint4*)&Btab2[tid * 4] = qq;
    }
    const float w1r0 = wh1b[(size_t)b * N_ + i0 + m];
    const float w1r1 = wh1b[(size_t)b * N_ + i0 + 16 + m];
    const float sb0 = w1r0 + Mh, sb1 = w1r1 + Mh;
    const float mr0 = fmaxf(sb0, ALPHA_ * sb0);
    const float mr1 = fmaxf(sb1, ALPHA_ * sb1);
    const float th0 = -w1r0, th1 = -w1r1;
    const unsigned short Fp0u = h2u((_Float16)__builtin_amdgcn_exp2f(sb0 - mr0));
    const unsigned short Fn0u = h2u((_Float16)__builtin_amdgcn_exp2f(ALPHA_ * sb0 - mr0));
    const unsigned short Fp1u = h2u((_Float16)__builtin_amdgcn_exp2f(sb1 - mr1));
    const unsigned short Fn1u = h2u((_Float16)__builtin_amdgcn_exp2f(ALPHA_ * sb1 - mr1));
    const unsigned short* wTb = whT2 + (size_t)b * 65536
                              + (size_t)(split * 16 + wv * 4) * 1024 + m * 64 + quad * 8;
    const float* wvb = wh2b + (size_t)b * N_ + split * 1024 + wv * 256 + quad * 8;
    f32x4 a0 = {0.f,0.f,0.f,0.f}, a1 = {0.f,0.f,0.f,0.f};
    f32x4 l0 = {0.f,0.f,0.f,0.f}, l1 = {0.f,0.f,0.f,0.f};
    f16x8 ones;
#pragma unroll
    for (int q = 0; q < 8; ++q) ones[q] = (_Float16)1.0f;
    __syncthreads();
#pragma unroll
    for (int q4 = 0; q4 < 4; ++q4) {
        const int half = q4 >> 1;
        unsigned int pw0, pw1, pw2, pw3, qw0, qw1, qw2, qw3;
        pw0 = ((const unsigned int*)&mask_s[m][wv*4+0])[half];
        pw1 = ((const unsigned int*)&mask_s[m][wv*4+1])[half];
        pw2 = ((const unsigned int*)&mask_s[m][wv*4+2])[half];
        pw3 = ((const unsigned int*)&mask_s[m][wv*4+3])[half];
        qw0 = ((const unsigned int*)&mask_s[m+16][wv*4+0])[half];
        qw1 = ((const unsigned int*)&mask_s[m+16][wv*4+1])[half];
        qw2 = ((const unsigned int*)&mask_s[m+16][wv*4+2])[half];
        qw3 = ((const unsigned int*)&mask_s[m+16][wv*4+3])[half];
        const unsigned short* bp = wTb + (size_t)q4 * 1024;
        const float* nw = wvb + q4 * 64;
#pragma unroll
        for (int ks = 0; ks < 2; ++ks) {
            f16x8 bb = *(const f16x8*)(bp + ks * 32);
            float wv8[8];
            *(float4*)&wv8[0] = *(const float4*)(nw + ks * 32);
            *(float4*)&wv8[4] = *(const float4*)(nw + ks * 32 + 4);
            unsigned int Bpk[8];
            {
                const unsigned int* Bb = &Btab2[wv * 256 + q4 * 64 + ks * 32 + quad * 8];
                *(uint4*)&Bpk[0] = *(const uint4*)Bb;
                *(uint4*)&Bpk[4] = *(const uint4*)(Bb + 4);
            }
            const int sh = ((16 * q4 + 8 * ks) & 31) + 2 * quad;
            const unsigned int gp0 = (pw0 >> sh) & 3u;
            const unsigned int gp1 = (pw1 >> sh) & 3u;
            const unsigned int gp2 = (pw2 >> sh) & 3u;
            const unsigned int gp3 = (pw3 >> sh) & 3u;
            const unsigned int gq0 = (qw0 >> sh) & 3u;
            const unsigned int gq1 = (qw1 >> sh) & 3u;
            const unsigned int gq2 = (qw2 >> sh) & 3u;
            const unsigned int gq3 = (qw3 >> sh) & 3u;
            f16x8 af0, af1;
#pragma unroll
            for (int jj = 0; jj < 8; ++jj) {
                const unsigned int bsel = 1u << (jj >> 2);
                const unsigned int gp = (jj&3)==0?gp0:(jj&3)==1?gp1:(jj&3)==2?gp2:gp3;
                const unsigned int gq = (jj&3)==0?gq0:(jj&3)==1?gq1:(jj&3)==2?gq2:gq3;
                const float w2v = wv8[jj];
                const unsigned int pk = Bpk[jj];
                const bool pos0 = (w2v > th0);
                _Float16 bh0 = u2h((unsigned short)(pos0 ? (pk & 0xffffu) : (pk >> 16)));
                _Float16 fh0 = u2h(pos0 ? Fp0u : Fn0u);
                _Float16 p0 = bh0 * fh0;
                af0[jj] = (((gp & bsel) == 0u) || (w2v == th0)) ? (_Float16)0.f : p0;
                const bool pos1 = (w2v > th1);
                _Float16 bh1 = u2h((unsigned short)(pos1 ? (pk & 0xffffu) : (pk >> 16)));
                _Float16 fh1 = u2h(pos1 ? Fp1u : Fn1u);
                _Float16 p1 = bh1 * fh1;
                af1[jj] = (((gq & bsel) == 0u) || (w2v == th1)) ? (_Float16)0.f : p1;
            }
            a0 = __builtin_amdgcn_mfma_f32_16x16x32_f16(af0, bb, a0, 0, 0, 0);
            l0 = __builtin_amdgcn_mfma_f32_16x16x32_f16(af0, ones, l0, 0, 0, 0);
            a1 = __builtin_amdgcn_mfma_f32_16x16x32_f16(af1, bb, a1, 0, 0, 0);
            l1 = __builtin_amdgcn_mfma_f32_16x16x32_f16(af1, ones, l1, 0, 0, 0);
        }
    }
#pragma unroll
    for (int reg = 0; reg < 4; ++reg) {
        accred[wv][quad * 4 + reg][m] = a0[reg];
        accred[wv][quad * 4 + reg + 16][m] = a1[reg];
    }
    if (m == 0) {
#pragma unroll
        for (int reg = 0; reg < 4; ++reg) {
            lred[wv][quad * 4 + reg] = l0[reg];
            lred[wv][quad * 4 + reg + 16] = l1[reg];
        }
    }
    __syncthreads();
    const int row = tid >> 4, col = tid & 15;
    float s0 = accred[0][row][col] + accred[1][row][col]
             + accred[2][row][col] + accred[3][row][col];
    float s1 = accred[0][row + 16][col] + accred[1][row + 16][col]
             + accred[2][row + 16][col] + accred[3][row + 16][col];
    float* op = outp + (((size_t)split * B_ + b) * N_ + i0) * EN_;
    op[(size_t)row * EN_ + col] = s0;
    op[(size_t)(row + 16) * EN_ + col] = s1;
    if (tid < 32) {
        float l = lred[0][tid] + lred[1][tid] + lred[2][tid] + lred[3][tid];
        outlp[((size_t)split * B_ + b) * N_ + i0 + tid] = l;
    }
}

// ---------- final: sum split partials, divide, ELU
__global__ __launch_bounds__(256) void finalize2_kernel(
    const float* __restrict__ outp, const float* __restrict__ outlp,
    float* __restrict__ out)
{
    const int id = blockIdx.x * 256 + threadIdx.x;      // B*N*EN
    const int gi = id >> 4;
    float num = 0.f, l = 0.f;
#pragma unroll
    for (int s = 0; s < S2_; ++s) {
        num += outp[(size_t)s * B_ * N_ * EN_ + id];
        l   += outlp[(size_t)s * B_ * N_ + gi];
    }
    float v = num / fmaxf(l, 1e-30f);
    out[id] = v > 0.f ? v : expm1f(v);
}

extern "C" void kernel_launch(void* const* d_in, const int* in_sizes, int n_in,
                              void* d_out, int out_size, void* d_ws, size_t ws_size,
                              hipStream_t stream)
{
    const float* fea = (const float*)d_in[0];
    const float* adj = (const float*)d_in[1];
    const float* Wh  = (const float*)d_in[2];
    const float* ah  = (const float*)d_in[3];
    const float* Wl  = (const float*)d_in[4];
    const float* al  = (const float*)d_in[5];

    float* p = (float*)d_ws;
    float* wh1   = p;  p += (size_t)B_ * H_ * N_;            // 32768
    float* wh2   = p;  p += (size_t)B_ * H_ * N_;            // 32768
    float* wh1b  = p;  p += (size_t)B_ * N_;                 // 8192
    float* wh2b  = p;  p += (size_t)B_ * N_;                 // 8192
    float* cmax1 = p;  p += (size_t)B_ * H_ * 128;           // 1024
    float* cmax2 = p;  p += (size_t)B_ * 256;                // 512
    float* l1p   = p;  p += (size_t)S1_ * B_ * N_ * H_;      // 131072
    float* x2p   = p;  p += (size_t)S1_ * B_ * N_ * D_;      // 4194304
    float* outp  = p;  p += (size_t)S2_ * B_ * N_ * EN_;     // 524288
    float* outlp = p;  p += (size_t)S2_ * B_ * N_;           // 32768
    unsigned long long* mask = (unsigned long long*)p;       // B*N*64 u64 = 4 MB
    unsigned short* whTt  = (unsigned short*)(mask + (size_t)B_ * N_ * 64);  // 2 MB
    unsigned short* whT2t = whTt + (size_t)B_ * H_ * 131072;                 // 256 KB

    prep_kernel<<<2048 + B_ * H_ * 128, 256, 0, stream>>>(adj, mask, fea, Wh, ah,
                                                          wh1, wh2, cmax1, whTt);
    attn1_kernel<<<dim3(N_ / 32, S1_, B_), 256, 0, stream>>>(mask, whTt, wh1, wh2, cmax1,
                                                             x2p, l1p);
    proj2_kernel<<<dim3(N_ / 16, B_), 256, 0, stream>>>(x2p, l1p, Wl, al,
                                                        wh1b, wh2b, cmax2, whT2t);
    attn2_kernel<<<dim3(N_ / 32, S2_, B_), 256, 0, stream>>>(mask, whT2t, wh1b, wh2b, cmax2,
                                                             outp, outlp);
    finalize2_kernel<<<(B_ * N_ * EN_) / 256, 256, 0, stream>>>(outp, outlp, (float*)d_out);
}

// Round 10
// 287.036 us; speedup vs baseline: 1.0370x; 1.0287x over previous
//
#include <hip/hip_runtime.h>
#include <hip/hip_bf16.h>
#include <stdint.h>

#define B_ 2
#define N_ 4096
#define D_ 128
#define H_ 4
#define HID_ 32
#define EN_ 16
#define ALPHA_ 0.2f
#define S1_ 8
#define S2_ 4
#define LOG2E_ 1.4426950408889634f

typedef __attribute__((ext_vector_type(8))) _Float16 f16x8;
typedef __attribute__((ext_vector_type(4))) float f32x4;
typedef __attribute__((ext_vector_type(8))) unsigned short u16x8;

__device__ __forceinline__ unsigned short f2h(float v) {
    _Float16 h = (_Float16)v;
    return *(unsigned short*)&h;
}

// ---------- fused prep (R5 structure): blocks [0,2048) = adj->bitmask;
// [2048,3072) = layer-1 proj. BW-bound mask stream across 2048 blocks.
__global__ __launch_bounds__(256) void prep_kernel(
    const float* __restrict__ adj, unsigned long long* __restrict__ mask,
    const float* __restrict__ fea, const float* __restrict__ Wh,
    const float* __restrict__ a_heads,
    float* __restrict__ wh1, float* __restrict__ wh2,
    float* __restrict__ cmax1, unsigned short* __restrict__ whTt)
{
    __shared__ float xs[32][132];          // 16.9 KB
    __shared__ float WT[32][132];          // 16.9 KB
    __shared__ float Wa[2][128];
    __shared__ float as_[2 * HID_];
    __shared__ unsigned short ts[32][32];  // [d][r]
    __shared__ float rmax[32];
    const int tid = threadIdx.x;

    if (blockIdx.x < 2048) {               // ---- mask part ----
        const int b = blockIdx.x >> 10, ib = blockIdx.x & 1023;
        const int i = ib * 4 + (tid >> 6);
        const int lane = tid & 63;
        const float* ar = adj + ((size_t)b * N_ + i) * N_;
        unsigned long long* mrow = mask + ((size_t)b * N_ + i) * 64;
#pragma unroll 4
        for (int c = 0; c < 16; ++c) {
            float4 v = *(const float4*)(ar + c * 256 + lane * 4);
            unsigned long long b0 = __ballot(v.x != 0.f);
            unsigned long long b1 = __ballot(v.y != 0.f);
            unsigned long long b2 = __ballot(v.z != 0.f);
            unsigned long long b3 = __ballot(v.w != 0.f);
            if (lane == 0) {
                ulonglong2 w01 = {b0, b1}, w23 = {b2, b3};
                *(ulonglong2*)(mrow + c * 4) = w01;
                *(ulonglong2*)(mrow + c * 4 + 2) = w23;
            }
        }
        return;
    }
    // ---- proj1 part: 32 rows x 32 cols, one head ----
    const int l0 = blockIdx.x - 2048;
    const int ib = l0 & 127, h = (l0 >> 7) & 3, b = l0 >> 9;
    const int i0 = ib * 32;
    const float* Wp = Wh + (size_t)h * D_ * HID_;
    for (int l = tid; l < 1024; l += 256) {          // W[k][d] -> WT[d][k]
        float4 w4 = *(const float4*)(Wp + l * 4);
        int k = l >> 3, d = (l & 7) * 4;
        WT[d][k] = w4.x; WT[d + 1][k] = w4.y; WT[d + 2][k] = w4.z; WT[d + 3][k] = w4.w;
    }
    if (tid < 2 * HID_) as_[tid] = a_heads[h * 2 * HID_ + tid];
    const float* xp = fea + ((size_t)b * N_ + i0) * D_;
    for (int l = tid; l < 1024; l += 256) {
        int r = l >> 5, k4 = (l & 31) * 4;
        *(float4*)&xs[r][k4] = *(const float4*)(xp + r * D_ + k4);
    }
    __syncthreads();
    // Wa[j][k] = sum_d W[k][d]*a[j*HID+d]
    {
        const int k = tid & 127, j = tid >> 7;
        const float* wr = Wp + k * HID_;
        const float* aw = &as_[j * HID_];
        float s = 0.f;
#pragma unroll
        for (int d = 0; d < HID_; d += 4) {
            float4 w4 = *(const float4*)(wr + d);
            s += w4.x * aw[d] + w4.y * aw[d + 1] + w4.z * aw[d + 2] + w4.w * aw[d + 3];
        }
        Wa[j][k] = s;
    }
    const int c = tid & 15, rg = (tid >> 4) * 2;     // rows rg,rg+1; cols c,c+16
    float a0[2] = {0.f, 0.f}, a1[2] = {0.f, 0.f};
#pragma unroll 8
    for (int k = 0; k < D_; k += 4) {
        float4 w0 = *(float4*)&WT[c][k];
        float4 w1 = *(float4*)&WT[c + 16][k];
#pragma unroll
        for (int i = 0; i < 2; ++i) {
            float4 x4 = *(float4*)&xs[rg + i][k];
            a0[i] += x4.x * w0.x + x4.y * w0.y + x4.z * w0.z + x4.w * w0.w;
            a1[i] += x4.x * w1.x + x4.y * w1.y + x4.z * w1.z + x4.w * w1.w;
        }
    }
#pragma unroll
    for (int i = 0; i < 2; ++i) {
        ts[c][rg + i] = f2h(a0[i]);
        ts[c + 16][rg + i] = f2h(a1[i]);
    }
    __syncthreads();                                 // Wa + ts ready
    {
        const int row = tid >> 3, q = tid & 7;       // 32 rows x 8 threads
        float d1 = 0.f, d2 = 0.f;
#pragma unroll
        for (int k = q * 16; k < q * 16 + 16; k += 4) {
            float4 x4 = *(float4*)&xs[row][k];
            float4 u = *(float4*)&Wa[0][k];
            float4 v = *(float4*)&Wa[1][k];
            d1 += x4.x * u.x + x4.y * u.y + x4.z * u.z + x4.w * u.w;
            d2 += x4.x * v.x + x4.y * v.y + x4.z * v.z + x4.w * v.w;
        }
        d1 += __shfl_xor(d1, 1); d1 += __shfl_xor(d1, 2); d1 += __shfl_xor(d1, 4);
        d2 += __shfl_xor(d2, 1); d2 += __shfl_xor(d2, 2); d2 += __shfl_xor(d2, 4);
        if (q == 0) {
            const size_t o = (size_t)(b * H_ + h) * N_ + i0 + row;
            wh1[o] = d1 * LOG2E_;
            wh2[o] = d2 * LOG2E_;
            rmax[row] = d2 * LOG2E_;
        }
    }
    __syncthreads();
    if (tid < 128) {                                 // whT tile out (1024 halfwords)
        const int d = tid >> 2, part = (tid & 3) * 8;
        unsigned short* dst = whTt + ((size_t)(b * H_ + h) * 64 + (i0 >> 6)) * 2048
                            + d * 64 + (i0 & 63) + part;
        *(u16x8*)dst = *(u16x8*)&ts[d][part];
    }
    if (tid < 32) {
        float mx = rmax[tid];
#pragma unroll
        for (int off = 16; off; off >>= 1) mx = fmaxf(mx, __shfl_xor(mx, off));
        if (tid == 0) cmax1[(size_t)(b * H_ + h) * 128 + ib] = mx;
    }
}

// ---------- layer-1 fused MFMA attention.
// R10 (counters-driven): R5's cheap f32 inner loop was latency-bound at 43%
// occupancy (LDS 36.9KB -> 4 blocks/CU); R9 proved occupancy is the lever but
// paid for it with inner-loop f16 ALU. This version keeps the R5 inner loop
// EXACTLY and raises occupancy by halving the per-block j-extent: S1 4->8
// splits of 512 j. Btab [H][2][512] f32 = 16KB, mask_s [32][9] = 2.3KB ->
// 18.7KB LDS -> 8 blocks/CU = 100% occupancy at VGPR=64.
__global__ __launch_bounds__(256) void attn1_kernel(
    const unsigned long long* __restrict__ mask, const unsigned short* __restrict__ whT,
    const float* __restrict__ wh1, const float* __restrict__ wh2,
    const float* __restrict__ cmax1,
    float* __restrict__ x2p, float* __restrict__ l1p)
{
    __shared__ unsigned long long mask_s[32][9];
    __shared__ float Btab[H_][2][512];     // 16 KB: per-head (B, B') tables
    const int b = blockIdx.z, split = blockIdx.y, i0 = blockIdx.x * 32;
    const int tid = threadIdx.x, lane = tid & 63, h = tid >> 6;
    const int m = lane & 15, quad = lane >> 4;
    {
        const int r = tid >> 3, w = tid & 7;
        mask_s[r][w] = mask[((size_t)b * N_ + i0 + r) * 64 + split * 8 + w];
    }
    const float* cm = cmax1 + (size_t)(b * H_ + h) * 128;
    float Mh = fmaxf(cm[lane], cm[lane + 64]);
#pragma unroll
    for (int off = 32; off; off >>= 1) Mh = fmaxf(Mh, __shfl_xor(Mh, off));
    const size_t bhN = (size_t)(b * H_ + h) * N_;
    // fill this head's (B, B') table: 512 j's, 8 per lane
    const float* w2g = wh2 + bhN + split * 512;
#pragma unroll
    for (int g = 0; g < 2; ++g) {
        float4 v = *(const float4*)(w2g + g * 256 + lane * 4);
        float4 eb, ep;
        eb.x = __builtin_amdgcn_exp2f(v.x - Mh);
        eb.y = __builtin_amdgcn_exp2f(v.y - Mh);
        eb.z = __builtin_amdgcn_exp2f(v.z - Mh);
        eb.w = __builtin_amdgcn_exp2f(v.w - Mh);
        ep.x = __builtin_amdgcn_exp2f(ALPHA_ * (v.x - Mh));
        ep.y = __builtin_amdgcn_exp2f(ALPHA_ * (v.y - Mh));
        ep.z = __builtin_amdgcn_exp2f(ALPHA_ * (v.z - Mh));
        ep.w = __builtin_amdgcn_exp2f(ALPHA_ * (v.w - Mh));
        *(float4*)&Btab[h][0][g * 256 + lane * 4] = eb;
        *(float4*)&Btab[h][1][g * 256 + lane * 4] = ep;
    }
    const float w1r0 = wh1[bhN + i0 + m];
    const float w1r1 = wh1[bhN + i0 + 16 + m];
    const float sb0 = w1r0 + Mh, sb1 = w1r1 + Mh;
    const float mr0 = fmaxf(sb0, ALPHA_ * sb0);
    const float mr1 = fmaxf(sb1, ALPHA_ * sb1);
    const float th0 = -w1r0, th1 = -w1r1;
    const float Fp0 = __builtin_amdgcn_exp2f(sb0 - mr0);
    const float Fn0 = __builtin_amdgcn_exp2f(ALPHA_ * sb0 - mr0);
    const float Fp1 = __builtin_amdgcn_exp2f(sb1 - mr1);
    const float Fn1 = __builtin_amdgcn_exp2f(ALPHA_ * sb1 - mr1);
    const float* wvb = wh2 + bhN + split * 512 + quad * 8;
    const unsigned short* bpb = whT + (size_t)(b * H_ + h) * 131072
                              + (size_t)split * 8 * 2048 + m * 64 + quad * 8;
    f32x4 a00 = {0.f,0.f,0.f,0.f}, a01 = {0.f,0.f,0.f,0.f}, a02 = {0.f,0.f,0.f,0.f};
    f32x4 a10 = {0.f,0.f,0.f,0.f}, a11 = {0.f,0.f,0.f,0.f}, a12 = {0.f,0.f,0.f,0.f};
    f16x8 ones;
#pragma unroll
    for (int q = 0; q < 8; ++q) ones[q] = (_Float16)1.0f;
    __syncthreads();

    for (int c = 0; c < 2; ++c) {
#pragma unroll
        for (int q4 = 0; q4 < 4; ++q4) {
            const int t = c * 4 + q4;
            const int half = q4 >> 1;                // dword half of the 64-bit word
            unsigned int pw0, pw1, pw2, pw3, qw0, qw1, qw2, qw3;
            pw0 = ((const unsigned int*)&mask_s[m][c*4+0])[half];
            pw1 = ((const unsigned int*)&mask_s[m][c*4+1])[half];
            pw2 = ((const unsigned int*)&mask_s[m][c*4+2])[half];
            pw3 = ((const unsigned int*)&mask_s[m][c*4+3])[half];
            qw0 = ((const unsigned int*)&mask_s[m+16][c*4+0])[half];
            qw1 = ((const unsigned int*)&mask_s[m+16][c*4+1])[half];
            qw2 = ((const unsigned int*)&mask_s[m+16][c*4+2])[half];
            qw3 = ((const unsigned int*)&mask_s[m+16][c*4+3])[half];
            const unsigned short* bp = bpb + (size_t)t * 2048;
            const float* nw = wvb + t * 64;
#pragma unroll
            for (int ks = 0; ks < 2; ++ks) {
                f16x8 bb0 = *(const f16x8*)(bp + ks * 32);
                f16x8 bb1 = *(const f16x8*)(bp + 1024 + ks * 32);
                float wv8[8];
                *(float4*)&wv8[0] = *(const float4*)(nw + ks * 32);
                *(float4*)&wv8[4] = *(const float4*)(nw + ks * 32 + 4);
                float Bj[8], Bp8[8];
                {
                    const float* Bb = &Btab[h][0][t * 64 + ks * 32 + quad * 8];
                    const float* Pb = &Btab[h][1][t * 64 + ks * 32 + quad * 8];
                    *(float4*)&Bj[0]  = *(const float4*)Bb;
                    *(float4*)&Bj[4]  = *(const float4*)(Bb + 4);
                    *(float4*)&Bp8[0] = *(const float4*)Pb;
                    *(float4*)&Bp8[4] = *(const float4*)(Pb + 4);
                }
                const int sh = ((16 * q4 + 8 * ks) & 31) + 2 * quad;
                const unsigned int gp0 = (pw0 >> sh) & 3u;
                const unsigned int gp1 = (pw1 >> sh) & 3u;
                const unsigned int gp2 = (pw2 >> sh) & 3u;
                const unsigned int gp3 = (pw3 >> sh) & 3u;
                const unsigned int gq0 = (qw0 >> sh) & 3u;
                const unsigned int gq1 = (qw1 >> sh) & 3u;
                const unsigned int gq2 = (qw2 >> sh) & 3u;
                const unsigned int gq3 = (qw3 >> sh) & 3u;
                f16x8 af0, af1;
#pragma unroll
                for (int qq = 0; qq < 4; ++qq) {
                    float r0p[2], r1p[2];
#pragma unroll
                    for (int cc = 0; cc < 2; ++cc) {
                        const int jj = qq * 2 + cc;
                        const unsigned int bsel = 1u << (jj >> 2);
                        const unsigned int gp = (jj&3)==0?gp0:(jj&3)==1?gp1:(jj&3)==2?gp2:gp3;
                        const unsigned int gq = (jj&3)==0?gq0:(jj&3)==1?gq1:(jj&3)==2?gq2:gq3;
                        const float w2v = wv8[jj];
                        float v0s = (w2v > th0) ? Fp0 * Bj[jj] : Fn0 * Bp8[jj];
                        r0p[cc] = ((gp & bsel) == 0u || w2v == th0) ? 0.f : v0s;
                        float v1s = (w2v > th1) ? Fp1 * Bj[jj] : Fn1 * Bp8[jj];
                        r1p[cc] = ((gq & bsel) == 0u || w2v == th1) ? 0.f : v1s;
                    }
                    auto pr0 = __builtin_amdgcn_cvt_pkrtz(r0p[0], r0p[1]);
                    af0[qq*2] = (_Float16)pr0[0]; af0[qq*2+1] = (_Float16)pr0[1];
                    auto pr1 = __builtin_amdgcn_cvt_pkrtz(r1p[0], r1p[1]);
                    af1[qq*2] = (_Float16)pr1[0]; af1[qq*2+1] = (_Float16)pr1[1];
                }
                a00 = __builtin_amdgcn_mfma_f32_16x16x32_f16(af0, bb0, a00, 0, 0, 0);
                a01 = __builtin_amdgcn_mfma_f32_16x16x32_f16(af0, bb1, a01, 0, 0, 0);
                a02 = __builtin_amdgcn_mfma_f32_16x16x32_f16(af0, ones, a02, 0, 0, 0);
                a10 = __builtin_amdgcn_mfma_f32_16x16x32_f16(af1, bb0, a10, 0, 0, 0);
                a11 = __builtin_amdgcn_mfma_f32_16x16x32_f16(af1, bb1, a11, 0, 0, 0);
                a12 = __builtin_amdgcn_mfma_f32_16x16x32_f16(af1, ones, a12, 0, 0, 0);
            }
        }
    }
    float* xp = x2p + (((size_t)split * B_ + b) * N_ + i0) * D_ + h * HID_;
#pragma unroll
    for (int reg = 0; reg < 4; ++reg) {
        const int row = quad * 4 + reg;
        xp[(size_t)row * D_ + m] = a00[reg];
        xp[(size_t)row * D_ + 16 + m] = a01[reg];
        xp[(size_t)(row + 16) * D_ + m] = a10[reg];
        xp[(size_t)(row + 16) * D_ + 16 + m] = a11[reg];
    }
    if (m == 0) {
        float* lp = l1p + (((size_t)split * B_ + b) * N_ + i0) * H_ + h;
#pragma unroll
        for (int reg = 0; reg < 4; ++reg) {
            lp[(size_t)(quad * 4 + reg) * H_] = a02[reg];
            lp[(size_t)(quad * 4 + reg + 16) * H_] = a12[reg];
        }
    }
}

// ---------- merged layer-2 projection (S1_=8 partials now)
__global__ __launch_bounds__(256) void proj2_kernel(
    const float* __restrict__ x2p, const float* __restrict__ l1p,
    const float* __restrict__ Wl, const float* __restrict__ a_last,
    float* __restrict__ wh1b, float* __restrict__ wh2b,
    float* __restrict__ cmax2, unsigned short* __restrict__ whT2t)
{
    __shared__ float Ws[D_ * EN_];
    __shared__ float xs[16][D_];
    __shared__ float as_[2 * EN_];
    __shared__ unsigned short ts[EN_][16];
    __shared__ float rmax[16];
    const int b = blockIdx.y, i0 = blockIdx.x * 16, tid = threadIdx.x;
    for (int idx = tid * 4; idx < D_ * EN_; idx += 1024)
        *(float4*)&Ws[idx] = *(const float4*)(Wl + idx);
    if (tid < 2 * EN_) as_[tid] = a_last[tid];
    for (int idx = tid * 4; idx < 16 * D_; idx += 1024) {
        const int r = idx >> 7, hd = idx & 127, h = hd >> 5;
        float4 v = {0.f, 0.f, 0.f, 0.f};
        float l = 0.f;
#pragma unroll
        for (int s = 0; s < S1_; ++s) {
            const size_t gi = ((size_t)s * B_ + b) * N_ + i0 + r;
            float4 p = *(const float4*)(x2p + gi * D_ + hd);
            v.x += p.x; v.y += p.y; v.z += p.z; v.w += p.w;
            l += l1p[gi * H_ + h];
        }
        float linv = 1.f / fmaxf(l, 1e-30f);
        float o0 = v.x * linv, o1 = v.y * linv, o2 = v.z * linv, o3 = v.w * linv;
        xs[r][hd]     = o0 > 0.f ? o0 : expm1f(o0);
        xs[r][hd + 1] = o1 > 0.f ? o1 : expm1f(o1);
        xs[r][hd + 2] = o2 > 0.f ? o2 : expm1f(o2);
        xs[r][hd + 3] = o3 > 0.f ? o3 : expm1f(o3);
    }
    __syncthreads();
    const int r = tid >> 4, e = tid & 15;
    float acc = 0.f;
#pragma unroll 8
    for (int k = 0; k < D_; ++k) acc += xs[r][k] * Ws[k * EN_ + e];
    ts[e][r] = f2h(acc);
    float d1 = acc * as_[e], d2 = acc * as_[EN_ + e];
#pragma unroll
    for (int off = 8; off; off >>= 1) {
        d1 += __shfl_xor(d1, off);
        d2 += __shfl_xor(d2, off);
    }
    d1 *= LOG2E_; d2 *= LOG2E_;
    if (e == 0) {
        wh1b[(size_t)b * N_ + i0 + r] = d1;
        wh2b[(size_t)b * N_ + i0 + r] = d2;
        rmax[r] = d2;
    }
    __syncthreads();
    if (tid < EN_) {
        unsigned short* dst = whT2t + (size_t)b * 65536
                            + (i0 >> 6) * 1024 + tid * 64 + (i0 & 63);
        *(u16x8*)dst = *(u16x8*)&ts[tid][0];
        *(u16x8*)(dst + 8) = *(u16x8*)&ts[tid][8];
    }
    if (tid == 0) {
        float mx = rmax[0];
#pragma unroll
        for (int k = 1; k < 16; ++k) mx = fmaxf(mx, rmax[k]);
        cmax2[(size_t)b * 256 + blockIdx.x] = mx;
    }
}

// ---------- layer-2 fused MFMA attention (R5 exact: f32 Btab2, f32 inner)
__global__ __launch_bounds__(256) void attn2_kernel(
    const unsigned long long* __restrict__ mask, const unsigned short* __restrict__ whT2,
    const float* __restrict__ wh1b, const float* __restrict__ wh2b,
    const float* __restrict__ cmax2,
    float* __restrict__ outp, float* __restrict__ outlp)
{
    __shared__ unsigned long long mask_s[32][17];
    __shared__ float accred[4][32][17];
    __shared__ float lred[4][32];
    __shared__ float Btab2[2][1024];       // 8 KB
    const int b = blockIdx.z, split = blockIdx.y, i0 = blockIdx.x * 32;
    const int tid = threadIdx.x, lane = tid & 63, wv = tid >> 6;
    const int m = lane & 15, quad = lane >> 4;
    {
        const int r = tid >> 3, w = (tid & 7) * 2;
        ulonglong2 mw = *(const ulonglong2*)(mask + ((size_t)b * N_ + i0 + r) * 64
                                             + split * 16 + w);
        mask_s[r][w] = mw.x; mask_s[r][w + 1] = mw.y;
    }
    const float* cm = cmax2 + (size_t)b * 256;
    float4 c0 = *(const float4*)(cm + lane * 4);
    float Mh = fmaxf(fmaxf(c0.x, c0.y), fmaxf(c0.z, c0.w));
#pragma unroll
    for (int off = 32; off; off >>= 1) Mh = fmaxf(Mh, __shfl_xor(Mh, off));
    // fill shared (B, B') table: 4 j's per thread
    {
        float4 v = *(const float4*)(wh2b + (size_t)b * N_ + split * 1024 + tid * 4);
        float4 eb, ep;
        eb.x = __builtin_amdgcn_exp2f(v.x - Mh);
        eb.y = __builtin_amdgcn_exp2f(v.y - Mh);
        eb.z = __builtin_amdgcn_exp2f(v.z - Mh);
        eb.w = __builtin_amdgcn_exp2f(v.w - Mh);
        ep.x = __builtin_amdgcn_exp2f(ALPHA_ * (v.x - Mh));
        ep.y = __builtin_amdgcn_exp2f(ALPHA_ * (v.y - Mh));
        ep.z = __builtin_amdgcn_exp2f(ALPHA_ * (v.z - Mh));
        ep.w = __builtin_amdgcn_exp2f(ALPHA_ * (v.w - Mh));
        *(float4*)&Btab2[0][tid * 4] = eb;
        *(float4*)&Btab2[1][tid * 4] = ep;
    }
    const float w1r0 = wh1b[(size_t)b * N_ + i0 + m];
    const float w1r1 = wh1b[(size_t)b * N_ + i0 + 16 + m];
    const float sb0 = w1r0 + Mh, sb1 = w1r1 + Mh;
    const float mr0 = fmaxf(sb0, ALPHA_ * sb0);
    const float mr1 = fmaxf(sb1, ALPHA_ * sb1);
    const float th0 = -w1r0, th1 = -w1r1;
    const float Fp0 = __builtin_amdgcn_exp2f(sb0 - mr0);
    const float Fn0 = __builtin_amdgcn_exp2f(ALPHA_ * sb0 - mr0);
    const float Fp1 = __builtin_amdgcn_exp2f(sb1 - mr1);
    const float Fn1 = __builtin_amdgcn_exp2f(ALPHA_ * sb1 - mr1);
    const unsigned short* wTb = whT2 + (size_t)b * 65536
                              + (size_t)(split * 16 + wv * 4) * 1024 + m * 64 + quad * 8;
    const float* wvb = wh2b + (size_t)b * N_ + split * 1024 + wv * 256 + quad * 8;
    f32x4 a0 = {0.f,0.f,0.f,0.f}, a1 = {0.f,0.f,0.f,0.f};
    f32x4 l0 = {0.f,0.f,0.f,0.f}, l1 = {0.f,0.f,0.f,0.f};
    f16x8 ones;
#pragma unroll
    for (int q = 0; q < 8; ++q) ones[q] = (_Float16)1.0f;
    __syncthreads();
#pragma unroll
    for (int q4 = 0; q4 < 4; ++q4) {
        const int half = q4 >> 1;
        unsigned int pw0, pw1, pw2, pw3, qw0, qw1, qw2, qw3;
        pw0 = ((const unsigned int*)&mask_s[m][wv*4+0])[half];
        pw1 = ((const unsigned int*)&mask_s[m][wv*4+1])[half];
        pw2 = ((const unsigned int*)&mask_s[m][wv*4+2])[half];
        pw3 = ((const unsigned int*)&mask_s[m][wv*4+3])[half];
        qw0 = ((const unsigned int*)&mask_s[m+16][wv*4+0])[half];
        qw1 = ((const unsigned int*)&mask_s[m+16][wv*4+1])[half];
        qw2 = ((const unsigned int*)&mask_s[m+16][wv*4+2])[half];
        qw3 = ((const unsigned int*)&mask_s[m+16][wv*4+3])[half];
        const unsigned short* bp = wTb + (size_t)q4 * 1024;
        const float* nw = wvb + q4 * 64;
#pragma unroll
        for (int ks = 0; ks < 2; ++ks) {
            f16x8 bb = *(const f16x8*)(bp + ks * 32);
            float wv8[8];
            *(float4*)&wv8[0] = *(const float4*)(nw + ks * 32);
            *(float4*)&wv8[4] = *(const float4*)(nw + ks * 32 + 4);
            float Bj[8], Bp8[8];
            {
                const float* Bb = &Btab2[0][wv * 256 + q4 * 64 + ks * 32 + quad * 8];
                const float* Pb = &Btab2[1][wv * 256 + q4 * 64 + ks * 32 + quad * 8];
                *(float4*)&Bj[0]  = *(const float4*)Bb;
                *(float4*)&Bj[4]  = *(const float4*)(Bb + 4);
                *(float4*)&Bp8[0] = *(const float4*)Pb;
                *(float4*)&Bp8[4] = *(const float4*)(Pb + 4);
            }
            const int sh = ((16 * q4 + 8 * ks) & 31) + 2 * quad;
            const unsigned int gp0 = (pw0 >> sh) & 3u;
            const unsigned int gp1 = (pw1 >> sh) & 3u;
            const unsigned int gp2 = (pw2 >> sh) & 3u;
            const unsigned int gp3 = (pw3 >> sh) & 3u;
            const unsigned int gq0 = (qw0 >> sh) & 3u;
            const unsigned int gq1 = (qw1 >> sh) & 3u;
            const unsigned int gq2 = (qw2 >> sh) & 3u;
            const unsigned int gq3 = (qw3 >> sh) & 3u;
            f16x8 af0, af1;
#pragma unroll
            for (int qq = 0; qq < 4; ++qq) {
                float r0p[2], r1p[2];
#pragma unroll
                for (int cc = 0; cc < 2; ++cc) {
                    const int jj = qq * 2 + cc;
                    const unsigned int bsel = 1u << (jj >> 2);
                    const unsigned int gp = (jj&3)==0?gp0:(jj&3)==1?gp1:(jj&3)==2?gp2:gp3;
                    const unsigned int gq = (jj&3)==0?gq0:(jj&3)==1?gq1:(jj&3)==2?gq2:gq3;
                    const float w2v = wv8[jj];
                    float v0s = (w2v > th0) ? Fp0 * Bj[jj] : Fn0 * Bp8[jj];
                    r0p[cc] = ((gp & bsel) == 0u || w2v == th0) ? 0.f : v0s;
                    float v1s = (w2v > th1) ? Fp1 * Bj[jj] : Fn1 * Bp8[jj];
                    r1p[cc] = ((gq & bsel) == 0u || w2v == th1) ? 0.f : v1s;
                }
                auto pr0 = __builtin_amdgcn_cvt_pkrtz(r0p[0], r0p[1]);
                af0[qq*2] = (_Float16)pr0[0]; af0[qq*2+1] = (_Float16)pr0[1];
                auto pr1 = __builtin_amdgcn_cvt_pkrtz(r1p[0], r1p[1]);
                af1[qq*2] = (_Float16)pr1[0]; af1[qq*2+1] = (_Float16)pr1[1];
            }
            a0 = __builtin_amdgcn_mfma_f32_16x16x32_f16(af0, bb, a0, 0, 0, 0);
            l0 = __builtin_amdgcn_mfma_f32_16x16x32_f16(af0, ones, l0, 0, 0, 0);
            a1 = __builtin_amdgcn_mfma_f32_16x16x32_f16(af1, bb, a1, 0, 0, 0);
            l1 = __builtin_amdgcn_mfma_f32_16x16x32_f16(af1, ones, l1, 0, 0, 0);
        }
    }
#pragma unroll
    for (int reg = 0; reg < 4; ++reg) {
        accred[wv][quad * 4 + reg][m] = a0[reg];
        accred[wv][quad * 4 + reg + 16][m] = a1[reg];
    }
    if (m == 0) {
#pragma unroll
        for (int reg = 0; reg < 4; ++reg) {
            lred[wv][quad * 4 + reg] = l0[reg];
            lred[wv][quad * 4 + reg + 16] = l1[reg];
        }
    }
    __syncthreads();
    const int row = tid >> 4, col = tid & 15;
    float s0 = accred[0][row][col] + accred[1][row][col]
             + accred[2][row][col] + accred[3][row][col];
    float s1 = accred[0][row + 16][col] + accred[1][row + 16][col]
             + accred[2][row + 16][col] + accred[3][row + 16][col];
    float* op = outp + (((size_t)split * B_ + b) * N_ + i0) * EN_;
    op[(size_t)row * EN_ + col] = s0;
    op[(size_t)(row + 16) * EN_ + col] = s1;
    if (tid < 32) {
        float l = lred[0][tid] + lred[1][tid] + lred[2][tid] + lred[3][tid];
        outlp[((size_t)split * B_ + b) * N_ + i0 + tid] = l;
    }
}

// ---------- final: sum split partials, divide, ELU
__global__ __launch_bounds__(256) void finalize2_kernel(
    const float* __restrict__ outp, const float* __restrict__ outlp,
    float* __restrict__ out)
{
    const int id = blockIdx.x * 256 + threadIdx.x;      // B*N*EN
    const int gi = id >> 4;
    float num = 0.f, l = 0.f;
#pragma unroll
    for (int s = 0; s < S2_; ++s) {
        num += outp[(size_t)s * B_ * N_ * EN_ + id];
        l   += outlp[(size_t)s * B_ * N_ + gi];
    }
    float v = num / fmaxf(l, 1e-30f);
    out[id] = v > 0.f ? v : expm1f(v);
}

extern "C" void kernel_launch(void* const* d_in, const int* in_sizes, int n_in,
                              void* d_out, int out_size, void* d_ws, size_t ws_size,
                              hipStream_t stream)
{
    const float* fea = (const float*)d_in[0];
    const float* adj = (const float*)d_in[1];
    const float* Wh  = (const float*)d_in[2];
    const float* ah  = (const float*)d_in[3];
    const float* Wl  = (const float*)d_in[4];
    const float* al  = (const float*)d_in[5];

    float* p = (float*)d_ws;
    float* wh1   = p;  p += (size_t)B_ * H_ * N_;            // 32768
    float* wh2   = p;  p += (size_t)B_ * H_ * N_;            // 32768
    float* wh1b  = p;  p += (size_t)B_ * N_;                 // 8192
    float* wh2b  = p;  p += (size_t)B_ * N_;                 // 8192
    float* cmax1 = p;  p += (size_t)B_ * H_ * 128;           // 1024
    float* cmax2 = p;  p += (size_t)B_ * 256;                // 512
    float* l1p   = p;  p += (size_t)S1_ * B_ * N_ * H_;      // 262144
    float* x2p   = p;  p += (size_t)S1_ * B_ * N_ * D_;      // 8388608
    float* outp  = p;  p += (size_t)S2_ * B_ * N_ * EN_;     // 524288
    float* outlp = p;  p += (size_t)S2_ * B_ * N_;           // 32768
    unsigned long long* mask = (unsigned long long*)p;       // B*N*64 u64 = 4 MB
    unsigned short* whTt  = (unsigned short*)(mask + (size_t)B_ * N_ * 64);  // 2 MB
    unsigned short* whT2t = whTt + (size_t)B_ * H_ * 131072;                 // 256 KB

    prep_kernel<<<2048 + B_ * H_ * 128, 256, 0, stream>>>(adj, mask, fea, Wh, ah,
                                                          wh1, wh2, cmax1, whTt);
    attn1_kernel<<<dim3(N_ / 32, S1_, B_), 256, 0, stream>>>(mask, whTt, wh1, wh2, cmax1,
                                                             x2p, l1p);
    proj2_kernel<<<dim3(N_ / 16, B_), 256, 0, stream>>>(x2p, l1p, Wl, al,
                                                        wh1b, wh2b, cmax2, whT2t);
    attn2_kernel<<<dim3(N_ / 32, S2_, B_), 256, 0, stream>>>(mask, whT2t, wh1b, wh2b, cmax2,
                                                             outp, outlp);
    finalize2_kernel<<<(B_ * N_ * EN_) / 256, 256, 0, stream>>>(outp, outlp, (float*)d_out);
}

// Round 11
// 277.450 us; speedup vs baseline: 1.0728x; 1.0345x over previous
//
#include <hip/hip_runtime.h>
#include <hip/hip_bf16.h>
#include <stdint.h>

#define B_ 2
#define N_ 4096
#define D_ 128
#define H_ 4
#define HID_ 32
#define EN_ 16
#define ALPHA_ 0.2f
#define S1_ 4
#define S2_ 4
#define LOG2E_ 1.4426950408889634f

typedef __attribute__((ext_vector_type(8))) _Float16 f16x8;
typedef __attribute__((ext_vector_type(4))) float f32x4;
typedef __attribute__((ext_vector_type(8))) unsigned short u16x8;

__device__ __forceinline__ unsigned short f2h(float v) {
    _Float16 h = (_Float16)v;
    return *(unsigned short*)&h;
}

// ---------- fused prep (R5 exact): blocks [0,2048) = adj->bitmask;
// [2048,3072) = layer-1 proj.
__global__ __launch_bounds__(256) void prep_kernel(
    const float* __restrict__ adj, unsigned long long* __restrict__ mask,
    const float* __restrict__ fea, const float* __restrict__ Wh,
    const float* __restrict__ a_heads,
    float* __restrict__ wh1, float* __restrict__ wh2,
    float* __restrict__ cmax1, unsigned short* __restrict__ whTt)
{
    __shared__ float xs[32][132];          // 16.9 KB
    __shared__ float WT[32][132];          // 16.9 KB
    __shared__ float Wa[2][128];
    __shared__ float as_[2 * HID_];
    __shared__ unsigned short ts[32][32];  // [d][r]
    __shared__ float rmax[32];
    const int tid = threadIdx.x;

    if (blockIdx.x < 2048) {               // ---- mask part ----
        const int b = blockIdx.x >> 10, ib = blockIdx.x & 1023;
        const int i = ib * 4 + (tid >> 6);
        const int lane = tid & 63;
        const float* ar = adj + ((size_t)b * N_ + i) * N_;
        unsigned long long* mrow = mask + ((size_t)b * N_ + i) * 64;
#pragma unroll 4
        for (int c = 0; c < 16; ++c) {
            float4 v = *(const float4*)(ar + c * 256 + lane * 4);
            unsigned long long b0 = __ballot(v.x != 0.f);
            unsigned long long b1 = __ballot(v.y != 0.f);
            unsigned long long b2 = __ballot(v.z != 0.f);
            unsigned long long b3 = __ballot(v.w != 0.f);
            if (lane == 0) {
                ulonglong2 w01 = {b0, b1}, w23 = {b2, b3};
                *(ulonglong2*)(mrow + c * 4) = w01;
                *(ulonglong2*)(mrow + c * 4 + 2) = w23;
            }
        }
        return;
    }
    // ---- proj1 part: 32 rows x 32 cols, one head ----
    const int l0 = blockIdx.x - 2048;
    const int ib = l0 & 127, h = (l0 >> 7) & 3, b = l0 >> 9;
    const int i0 = ib * 32;
    const float* Wp = Wh + (size_t)h * D_ * HID_;
    for (int l = tid; l < 1024; l += 256) {          // W[k][d] -> WT[d][k]
        float4 w4 = *(const float4*)(Wp + l * 4);
        int k = l >> 3, d = (l & 7) * 4;
        WT[d][k] = w4.x; WT[d + 1][k] = w4.y; WT[d + 2][k] = w4.z; WT[d + 3][k] = w4.w;
    }
    if (tid < 2 * HID_) as_[tid] = a_heads[h * 2 * HID_ + tid];
    const float* xp = fea + ((size_t)b * N_ + i0) * D_;
    for (int l = tid; l < 1024; l += 256) {
        int r = l >> 5, k4 = (l & 31) * 4;
        *(float4*)&xs[r][k4] = *(const float4*)(xp + r * D_ + k4);
    }
    __syncthreads();
    // Wa[j][k] = sum_d W[k][d]*a[j*HID+d]
    {
        const int k = tid & 127, j = tid >> 7;
        const float* wr = Wp + k * HID_;
        const float* aw = &as_[j * HID_];
        float s = 0.f;
#pragma unroll
        for (int d = 0; d < HID_; d += 4) {
            float4 w4 = *(const float4*)(wr + d);
            s += w4.x * aw[d] + w4.y * aw[d + 1] + w4.z * aw[d + 2] + w4.w * aw[d + 3];
        }
        Wa[j][k] = s;
    }
    const int c = tid & 15, rg = (tid >> 4) * 2;     // rows rg,rg+1; cols c,c+16
    float a0[2] = {0.f, 0.f}, a1[2] = {0.f, 0.f};
#pragma unroll 8
    for (int k = 0; k < D_; k += 4) {
        float4 w0 = *(float4*)&WT[c][k];
        float4 w1 = *(float4*)&WT[c + 16][k];
#pragma unroll
        for (int i = 0; i < 2; ++i) {
            float4 x4 = *(float4*)&xs[rg + i][k];
            a0[i] += x4.x * w0.x + x4.y * w0.y + x4.z * w0.z + x4.w * w0.w;
            a1[i] += x4.x * w1.x + x4.y * w1.y + x4.z * w1.z + x4.w * w1.w;
        }
    }
#pragma unroll
    for (int i = 0; i < 2; ++i) {
        ts[c][rg + i] = f2h(a0[i]);
        ts[c + 16][rg + i] = f2h(a1[i]);
    }
    __syncthreads();                                 // Wa + ts ready
    {
        const int row = tid >> 3, q = tid & 7;       // 32 rows x 8 threads
        float d1 = 0.f, d2 = 0.f;
#pragma unroll
        for (int k = q * 16; k < q * 16 + 16; k += 4) {
            float4 x4 = *(float4*)&xs[row][k];
            float4 u = *(float4*)&Wa[0][k];
            float4 v = *(float4*)&Wa[1][k];
            d1 += x4.x * u.x + x4.y * u.y + x4.z * u.z + x4.w * u.w;
            d2 += x4.x * v.x + x4.y * v.y + x4.z * v.z + x4.w * v.w;
        }
        d1 += __shfl_xor(d1, 1); d1 += __shfl_xor(d1, 2); d1 += __shfl_xor(d1, 4);
        d2 += __shfl_xor(d2, 1); d2 += __shfl_xor(d2, 2); d2 += __shfl_xor(d2, 4);
        if (q == 0) {
            const size_t o = (size_t)(b * H_ + h) * N_ + i0 + row;
            wh1[o] = d1 * LOG2E_;
            wh2[o] = d2 * LOG2E_;
            rmax[row] = d2 * LOG2E_;
        }
    }
    __syncthreads();
    if (tid < 128) {                                 // whT tile out (1024 halfwords)
        const int d = tid >> 2, part = (tid & 3) * 8;
        unsigned short* dst = whTt + ((size_t)(b * H_ + h) * 64 + (i0 >> 6)) * 2048
                            + d * 64 + (i0 & 63) + part;
        *(u16x8*)dst = *(u16x8*)&ts[d][part];
    }
    if (tid < 32) {
        float mx = rmax[tid];
#pragma unroll
        for (int off = 16; off; off >>= 1) mx = fmaxf(mx, __shfl_xor(mx, off));
        if (tid == 0) cmax1[(size_t)(b * H_ + h) * 128 + ib] = mx;
    }
}

// ---------- layer-1 fused MFMA attention.
// R11 (counters-driven): occupancy lever with ZERO tax. One head per block
// (grid z = B*H), 4 waves split the 1024-j range (wave wv owns t in
// [4wv,4wv+4)), partial accumulators reduced through LDS (attn2's proven
// pattern). Btab shrinks to [2][1024] f32 = 8KB; the accred reduction buffer
// OVERLAYS the dead mask_s/Btab region (barrier-separated). LDS =
// max(12.5KB, 18.9KB) = 18.9KB -> 8 blocks/CU = 100% occupancy (was 4/43%).
// Inner loop is byte-identical to R5's f32 form; no extra global traffic;
// exp2 total unchanged (tables were recomputed per i0-block anyway).
__global__ __launch_bounds__(256) void attn1_kernel(
    const unsigned long long* __restrict__ mask, const unsigned short* __restrict__ whT,
    const float* __restrict__ wh1, const float* __restrict__ wh2,
    const float* __restrict__ cmax1,
    float* __restrict__ x2p, float* __restrict__ l1p)
{
    __shared__ __align__(16) char smem[18944];
    unsigned long long (*mask_s)[17] = (unsigned long long(*)[17])smem;   // 4352 (phase1)
    float (*Btab)[1024] = (float(*)[1024])(smem + 4352);                  // 8192 (phase1)
    float (*accred)[32][36] = (float(*)[32][36])smem;                     // 18432 (phase2)
    float (*lred)[32] = (float(*)[32])(smem + 18432);                     // 512 (phase2)
    const int bh = blockIdx.z, b = bh >> 2, h = bh & 3;
    const int split = blockIdx.y, i0 = blockIdx.x * 32;
    const int tid = threadIdx.x, lane = tid & 63, wv = tid >> 6;
    const int m = lane & 15, quad = lane >> 4;
    {
        const int r = tid >> 3, w = (tid & 7) * 2;
        ulonglong2 mw = *(const ulonglong2*)(mask + ((size_t)b * N_ + i0 + r) * 64
                                             + split * 16 + w);
        mask_s[r][w] = mw.x; mask_s[r][w + 1] = mw.y;
    }
    const float* cm = cmax1 + (size_t)(b * H_ + h) * 128;
    float Mh = fmaxf(cm[lane], cm[lane + 64]);
#pragma unroll
    for (int off = 32; off; off >>= 1) Mh = fmaxf(Mh, __shfl_xor(Mh, off));
    const size_t bhN = (size_t)(b * H_ + h) * N_;
    // fill (B, B') table for this head: 4 j's per thread
    {
        float4 v = *(const float4*)(wh2 + bhN + split * 1024 + tid * 4);
        float4 eb, ep;
        eb.x = __builtin_amdgcn_exp2f(v.x - Mh);
        eb.y = __builtin_amdgcn_exp2f(v.y - Mh);
        eb.z = __builtin_amdgcn_exp2f(v.z - Mh);
        eb.w = __builtin_amdgcn_exp2f(v.w - Mh);
        ep.x = __builtin_amdgcn_exp2f(ALPHA_ * (v.x - Mh));
        ep.y = __builtin_amdgcn_exp2f(ALPHA_ * (v.y - Mh));
        ep.z = __builtin_amdgcn_exp2f(ALPHA_ * (v.z - Mh));
        ep.w = __builtin_amdgcn_exp2f(ALPHA_ * (v.w - Mh));
        *(float4*)&Btab[0][tid * 4] = eb;
        *(float4*)&Btab[1][tid * 4] = ep;
    }
    const float w1r0 = wh1[bhN + i0 + m];
    const float w1r1 = wh1[bhN + i0 + 16 + m];
    const float sb0 = w1r0 + Mh, sb1 = w1r1 + Mh;
    const float mr0 = fmaxf(sb0, ALPHA_ * sb0);
    const float mr1 = fmaxf(sb1, ALPHA_ * sb1);
    const float th0 = -w1r0, th1 = -w1r1;
    const float Fp0 = __builtin_amdgcn_exp2f(sb0 - mr0);
    const float Fn0 = __builtin_amdgcn_exp2f(ALPHA_ * sb0 - mr0);
    const float Fp1 = __builtin_amdgcn_exp2f(sb1 - mr1);
    const float Fn1 = __builtin_amdgcn_exp2f(ALPHA_ * sb1 - mr1);
    const float* wvb = wh2 + bhN + split * 1024 + quad * 8;
    const unsigned short* bpb = whT + (size_t)(b * H_ + h) * 131072
                              + (size_t)split * 16 * 2048 + m * 64 + quad * 8;
    f32x4 a00 = {0.f,0.f,0.f,0.f}, a01 = {0.f,0.f,0.f,0.f}, a02 = {0.f,0.f,0.f,0.f};
    f32x4 a10 = {0.f,0.f,0.f,0.f}, a11 = {0.f,0.f,0.f,0.f}, a12 = {0.f,0.f,0.f,0.f};
    f16x8 ones;
#pragma unroll
    for (int q = 0; q < 8; ++q) ones[q] = (_Float16)1.0f;
    __syncthreads();

#pragma unroll
    for (int q4 = 0; q4 < 4; ++q4) {
        const int t = wv * 4 + q4;
        const int half = q4 >> 1;                // dword half of the 64-bit word
        unsigned int pw0, pw1, pw2, pw3, qw0, qw1, qw2, qw3;
        pw0 = ((const unsigned int*)&mask_s[m][wv*4+0])[half];
        pw1 = ((const unsigned int*)&mask_s[m][wv*4+1])[half];
        pw2 = ((const unsigned int*)&mask_s[m][wv*4+2])[half];
        pw3 = ((const unsigned int*)&mask_s[m][wv*4+3])[half];
        qw0 = ((const unsigned int*)&mask_s[m+16][wv*4+0])[half];
        qw1 = ((const unsigned int*)&mask_s[m+16][wv*4+1])[half];
        qw2 = ((const unsigned int*)&mask_s[m+16][wv*4+2])[half];
        qw3 = ((const unsigned int*)&mask_s[m+16][wv*4+3])[half];
        const unsigned short* bp = bpb + (size_t)t * 2048;
        const float* nw = wvb + t * 64;
#pragma unroll
        for (int ks = 0; ks < 2; ++ks) {
            f16x8 bb0 = *(const f16x8*)(bp + ks * 32);
            f16x8 bb1 = *(const f16x8*)(bp + 1024 + ks * 32);
            float wv8[8];
            *(float4*)&wv8[0] = *(const float4*)(nw + ks * 32);
            *(float4*)&wv8[4] = *(const float4*)(nw + ks * 32 + 4);
            float Bj[8], Bp8[8];
            {
                const float* Bb = &Btab[0][t * 64 + ks * 32 + quad * 8];
                const float* Pb = &Btab[1][t * 64 + ks * 32 + quad * 8];
                *(float4*)&Bj[0]  = *(const float4*)Bb;
                *(float4*)&Bj[4]  = *(const float4*)(Bb + 4);
                *(float4*)&Bp8[0] = *(const float4*)Pb;
                *(float4*)&Bp8[4] = *(const float4*)(Pb + 4);
            }
            const int sh = ((16 * q4 + 8 * ks) & 31) + 2 * quad;
            const unsigned int gp0 = (pw0 >> sh) & 3u;
            const unsigned int gp1 = (pw1 >> sh) & 3u;
            const unsigned int gp2 = (pw2 >> sh) & 3u;
            const unsigned int gp3 = (pw3 >> sh) & 3u;
            const unsigned int gq0 = (qw0 >> sh) & 3u;
            const unsigned int gq1 = (qw1 >> sh) & 3u;
            const unsigned int gq2 = (qw2 >> sh) & 3u;
            const unsigned int gq3 = (qw3 >> sh) & 3u;
            f16x8 af0, af1;
#pragma unroll
            for (int qq = 0; qq < 4; ++qq) {
                float r0p[2], r1p[2];
#pragma unroll
                for (int cc = 0; cc < 2; ++cc) {
                    const int jj = qq * 2 + cc;
                    const unsigned int bsel = 1u << (jj >> 2);
                    const unsigned int gp = (jj&3)==0?gp0:(jj&3)==1?gp1:(jj&3)==2?gp2:gp3;
                    const unsigned int gq = (jj&3)==0?gq0:(jj&3)==1?gq1:(jj&3)==2?gq2:gq3;
                    const float w2v = wv8[jj];
                    float v0s = (w2v > th0) ? Fp0 * Bj[jj] : Fn0 * Bp8[jj];
                    r0p[cc] = ((gp & bsel) == 0u || w2v == th0) ? 0.f : v0s;
                    float v1s = (w2v > th1) ? Fp1 * Bj[jj] : Fn1 * Bp8[jj];
                    r1p[cc] = ((gq & bsel) == 0u || w2v == th1) ? 0.f : v1s;
                }
                auto pr0 = __builtin_amdgcn_cvt_pkrtz(r0p[0], r0p[1]);
                af0[qq*2] = (_Float16)pr0[0]; af0[qq*2+1] = (_Float16)pr0[1];
                auto pr1 = __builtin_amdgcn_cvt_pkrtz(r1p[0], r1p[1]);
                af1[qq*2] = (_Float16)pr1[0]; af1[qq*2+1] = (_Float16)pr1[1];
            }
            a00 = __builtin_amdgcn_mfma_f32_16x16x32_f16(af0, bb0, a00, 0, 0, 0);
            a01 = __builtin_amdgcn_mfma_f32_16x16x32_f16(af0, bb1, a01, 0, 0, 0);
            a02 = __builtin_amdgcn_mfma_f32_16x16x32_f16(af0, ones, a02, 0, 0, 0);
            a10 = __builtin_amdgcn_mfma_f32_16x16x32_f16(af1, bb0, a10, 0, 0, 0);
            a11 = __builtin_amdgcn_mfma_f32_16x16x32_f16(af1, bb1, a11, 0, 0, 0);
            a12 = __builtin_amdgcn_mfma_f32_16x16x32_f16(af1, ones, a12, 0, 0, 0);
        }
    }
    __syncthreads();                       // mask_s/Btab dead; safe to overlay
#pragma unroll
    for (int reg = 0; reg < 4; ++reg) {
        accred[wv][quad * 4 + reg][m]           = a00[reg];
        accred[wv][quad * 4 + reg][m + 16]      = a01[reg];
        accred[wv][quad * 4 + reg + 16][m]      = a10[reg];
        accred[wv][quad * 4 + reg + 16][m + 16] = a11[reg];
    }
    if (m == 0) {
#pragma unroll
        for (int reg = 0; reg < 4; ++reg) {
            lred[wv][quad * 4 + reg]      = a02[reg];
            lred[wv][quad * 4 + reg + 16] = a12[reg];
        }
    }
    __syncthreads();
    {
        const int row = tid >> 3, c4 = (tid & 7) * 4;
        float4 s0 = *(float4*)&accred[0][row][c4];
        float4 s1 = *(float4*)&accred[1][row][c4];
        float4 s2 = *(float4*)&accred[2][row][c4];
        float4 s3 = *(float4*)&accred[3][row][c4];
        float4 s;
        s.x = s0.x + s1.x + s2.x + s3.x;
        s.y = s0.y + s1.y + s2.y + s3.y;
        s.z = s0.z + s1.z + s2.z + s3.z;
        s.w = s0.w + s1.w + s2.w + s3.w;
        float* xp = x2p + (((size_t)split * B_ + b) * N_ + i0) * D_ + h * HID_;
        *(float4*)&xp[(size_t)row * D_ + c4] = s;
    }
    if (tid < 32) {
        float l = lred[0][tid] + lred[1][tid] + lred[2][tid] + lred[3][tid];
        l1p[(((size_t)split * B_ + b) * N_ + i0 + tid) * H_ + h] = l;
    }
}

// ---------- merged layer-2 projection (R5 exact, S1_=4)
__global__ __launch_bounds__(256) void proj2_kernel(
    const float* __restrict__ x2p, const float* __restrict__ l1p,
    const float* __restrict__ Wl, const float* __restrict__ a_last,
    float* __restrict__ wh1b, float* __restrict__ wh2b,
    float* __restrict__ cmax2, unsigned short* __restrict__ whT2t)
{
    __shared__ float Ws[D_ * EN_];
    __shared__ float xs[16][D_];
    __shared__ float as_[2 * EN_];
    __shared__ unsigned short ts[EN_][16];
    __shared__ float rmax[16];
    const int b = blockIdx.y, i0 = blockIdx.x * 16, tid = threadIdx.x;
    for (int idx = tid * 4; idx < D_ * EN_; idx += 1024)
        *(float4*)&Ws[idx] = *(const float4*)(Wl + idx);
    if (tid < 2 * EN_) as_[tid] = a_last[tid];
    for (int idx = tid * 4; idx < 16 * D_; idx += 1024) {
        const int r = idx >> 7, hd = idx & 127, h = hd >> 5;
        float4 v = {0.f, 0.f, 0.f, 0.f};
        float l = 0.f;
#pragma unroll
        for (int s = 0; s < S1_; ++s) {
            const size_t gi = ((size_t)s * B_ + b) * N_ + i0 + r;
            float4 p = *(const float4*)(x2p + gi * D_ + hd);
            v.x += p.x; v.y += p.y; v.z += p.z; v.w += p.w;
            l += l1p[gi * H_ + h];
        }
        float linv = 1.f / fmaxf(l, 1e-30f);
        float o0 = v.x * linv, o1 = v.y * linv, o2 = v.z * linv, o3 = v.w * linv;
        xs[r][hd]     = o0 > 0.f ? o0 : expm1f(o0);
        xs[r][hd + 1] = o1 > 0.f ? o1 : expm1f(o1);
        xs[r][hd + 2] = o2 > 0.f ? o2 : expm1f(o2);
        xs[r][hd + 3] = o3 > 0.f ? o3 : expm1f(o3);
    }
    __syncthreads();
    const int r = tid >> 4, e = tid & 15;
    float acc = 0.f;
#pragma unroll 8
    for (int k = 0; k < D_; ++k) acc += xs[r][k] * Ws[k * EN_ + e];
    ts[e][r] = f2h(acc);
    float d1 = acc * as_[e], d2 = acc * as_[EN_ + e];
#pragma unroll
    for (int off = 8; off; off >>= 1) {
        d1 += __shfl_xor(d1, off);
        d2 += __shfl_xor(d2, off);
    }
    d1 *= LOG2E_; d2 *= LOG2E_;
    if (e == 0) {
        wh1b[(size_t)b * N_ + i0 + r] = d1;
        wh2b[(size_t)b * N_ + i0 + r] = d2;
        rmax[r] = d2;
    }
    __syncthreads();
    if (tid < EN_) {
        unsigned short* dst = whT2t + (size_t)b * 65536
                            + (i0 >> 6) * 1024 + tid * 64 + (i0 & 63);
        *(u16x8*)dst = *(u16x8*)&ts[tid][0];
        *(u16x8*)(dst + 8) = *(u16x8*)&ts[tid][8];
    }
    if (tid == 0) {
        float mx = rmax[0];
#pragma unroll
        for (int k = 1; k < 16; ++k) mx = fmaxf(mx, rmax[k]);
        cmax2[(size_t)b * 256 + blockIdx.x] = mx;
    }
}

// ---------- layer-2 fused MFMA attention (R5 inner loop + overlay -> 8 blocks/CU)
__global__ __launch_bounds__(256) void attn2_kernel(
    const unsigned long long* __restrict__ mask, const unsigned short* __restrict__ whT2,
    const float* __restrict__ wh1b, const float* __restrict__ wh2b,
    const float* __restrict__ cmax2,
    float* __restrict__ outp, float* __restrict__ outlp)
{
    __shared__ __align__(16) char smem[12544];
    unsigned long long (*mask_s)[17] = (unsigned long long(*)[17])smem;   // 4352 (phase1)
    float (*Btab2)[1024] = (float(*)[1024])(smem + 4352);                 // 8192 (phase1)
    float (*accred)[32][17] = (float(*)[32][17])smem;                     // 8704 (phase2)
    float (*lred)[32] = (float(*)[32])(smem + 8704);                      // 512 (phase2)
    const int b = blockIdx.z, split = blockIdx.y, i0 = blockIdx.x * 32;
    const int tid = threadIdx.x, lane = tid & 63, wv = tid >> 6;
    const int m = lane & 15, quad = lane >> 4;
    {
        const int r = tid >> 3, w = (tid & 7) * 2;
        ulonglong2 mw = *(const ulonglong2*)(mask + ((size_t)b * N_ + i0 + r) * 64
                                             + split * 16 + w);
        mask_s[r][w] = mw.x; mask_s[r][w + 1] = mw.y;
    }
    const float* cm = cmax2 + (size_t)b * 256;
    float4 c0 = *(const float4*)(cm + lane * 4);
    float Mh = fmaxf(fmaxf(c0.x, c0.y), fmaxf(c0.z, c0.w));
#pragma unroll
    for (int off = 32; off; off >>= 1) Mh = fmaxf(Mh, __shfl_xor(Mh, off));
    // fill shared (B, B') table: 4 j's per thread
    {
        float4 v = *(const float4*)(wh2b + (size_t)b * N_ + split * 1024 + tid * 4);
        float4 eb, ep;
        eb.x = __builtin_amdgcn_exp2f(v.x - Mh);
        eb.y = __builtin_amdgcn_exp2f(v.y - Mh);
        eb.z = __builtin_amdgcn_exp2f(v.z - Mh);
        eb.w = __builtin_amdgcn_exp2f(v.w - Mh);
        ep.x = __builtin_amdgcn_exp2f(ALPHA_ * (v.x - Mh));
        ep.y = __builtin_amdgcn_exp2f(ALPHA_ * (v.y - Mh));
        ep.z = __builtin_amdgcn_exp2f(ALPHA_ * (v.z - Mh));
        ep.w = __builtin_amdgcn_exp2f(ALPHA_ * (v.w - Mh));
        *(float4*)&Btab2[0][tid * 4] = eb;
        *(float4*)&Btab2[1][tid * 4] = ep;
    }
    const float w1r0 = wh1b[(size_t)b * N_ + i0 + m];
    const float w1r1 = wh1b[(size_t)b * N_ + i0 + 16 + m];
    const float sb0 = w1r0 + Mh, sb1 = w1r1 + Mh;
    const float mr0 = fmaxf(sb0, ALPHA_ * sb0);
    const float mr1 = fmaxf(sb1, ALPHA_ * sb1);
    const float th0 = -w1r0, th1 = -w1r1;
    const float Fp0 = __builtin_amdgcn_exp2f(sb0 - mr0);
    const float Fn0 = __builtin_amdgcn_exp2f(ALPHA_ * sb0 - mr0);
    const float Fp1 = __builtin_amdgcn_exp2f(sb1 - mr1);
    const float Fn1 = __builtin_amdgcn_exp2f(ALPHA_ * sb1 - mr1);
    const unsigned short* wTb = whT2 + (size_t)b * 65536
                              + (size_t)(split * 16 + wv * 4) * 1024 + m * 64 + quad * 8;
    const float* wvb = wh2b + (size_t)b * N_ + split * 1024 + wv * 256 + quad * 8;
    f32x4 a0 = {0.f,0.f,0.f,0.f}, a1 = {0.f,0.f,0.f,0.f};
    f32x4 l0 = {0.f,0.f,0.f,0.f}, l1 = {0.f,0.f,0.f,0.f};
    f16x8 ones;
#pragma unroll
    for (int q = 0; q < 8; ++q) ones[q] = (_Float16)1.0f;
    __syncthreads();
#pragma unroll
    for (int q4 = 0; q4 < 4; ++q4) {
        const int half = q4 >> 1;
        unsigned int pw0, pw1, pw2, pw3, qw0, qw1, qw2, qw3;
        pw0 = ((const unsigned int*)&mask_s[m][wv*4+0])[half];
        pw1 = ((const unsigned int*)&mask_s[m][wv*4+1])[half];
        pw2 = ((const unsigned int*)&mask_s[m][wv*4+2])[half];
        pw3 = ((const unsigned int*)&mask_s[m][wv*4+3])[half];
        qw0 = ((const unsigned int*)&mask_s[m+16][wv*4+0])[half];
        qw1 = ((const unsigned int*)&mask_s[m+16][wv*4+1])[half];
        qw2 = ((const unsigned int*)&mask_s[m+16][wv*4+2])[half];
        qw3 = ((const unsigned int*)&mask_s[m+16][wv*4+3])[half];
        const unsigned short* bp = wTb + (size_t)q4 * 1024;
        const float* nw = wvb + q4 * 64;
#pragma unroll
        for (int ks = 0; ks < 2; ++ks) {
            f16x8 bb = *(const f16x8*)(bp + ks * 32);
            float wv8[8];
            *(float4*)&wv8[0] = *(const float4*)(nw + ks * 32);
            *(float4*)&wv8[4] = *(const float4*)(nw + ks * 32 + 4);
            float Bj[8], Bp8[8];
            {
                const float* Bb = &Btab2[0][wv * 256 + q4 * 64 + ks * 32 + quad * 8];
                const float* Pb = &Btab2[1][wv * 256 + q4 * 64 + ks * 32 + quad * 8];
                *(float4*)&Bj[0]  = *(const float4*)Bb;
                *(float4*)&Bj[4]  = *(const float4*)(Bb + 4);
                *(float4*)&Bp8[0] = *(const float4*)Pb;
                *(float4*)&Bp8[4] = *(const float4*)(Pb + 4);
            }
            const int sh = ((16 * q4 + 8 * ks) & 31) + 2 * quad;
            const unsigned int gp0 = (pw0 >> sh) & 3u;
            const unsigned int gp1 = (pw1 >> sh) & 3u;
            const unsigned int gp2 = (pw2 >> sh) & 3u;
            const unsigned int gp3 = (pw3 >> sh) & 3u;
            const unsigned int gq0 = (qw0 >> sh) & 3u;
            const unsigned int gq1 = (qw1 >> sh) & 3u;
            const unsigned int gq2 = (qw2 >> sh) & 3u;
            const unsigned int gq3 = (qw3 >> sh) & 3u;
            f16x8 af0, af1;
#pragma unroll
            for (int qq = 0; qq < 4; ++qq) {
                float r0p[2], r1p[2];
#pragma unroll
                for (int cc = 0; cc < 2; ++cc) {
                    const int jj = qq * 2 + cc;
                    const unsigned int bsel = 1u << (jj >> 2);
                    const unsigned int gp = (jj&3)==0?gp0:(jj&3)==1?gp1:(jj&3)==2?gp2:gp3;
                    const unsigned int gq = (jj&3)==0?gq0:(jj&3)==1?gq1:(jj&3)==2?gq2:gq3;
                    const float w2v = wv8[jj];
                    float v0s = (w2v > th0) ? Fp0 * Bj[jj] : Fn0 * Bp8[jj];
                    r0p[cc] = ((gp & bsel) == 0u || w2v == th0) ? 0.f : v0s;
                    float v1s = (w2v > th1) ? Fp1 * Bj[jj] : Fn1 * Bp8[jj];
                    r1p[cc] = ((gq & bsel) == 0u || w2v == th1) ? 0.f : v1s;
                }
                auto pr0 = __builtin_amdgcn_cvt_pkrtz(r0p[0], r0p[1]);
                af0[qq*2] = (_Float16)pr0[0]; af0[qq*2+1] = (_Float16)pr0[1];
                auto pr1 = __builtin_amdgcn_cvt_pkrtz(r1p[0], r1p[1]);
                af1[qq*2] = (_Float16)pr1[0]; af1[qq*2+1] = (_Float16)pr1[1];
            }
            a0 = __builtin_amdgcn_mfma_f32_16x16x32_f16(af0, bb, a0, 0, 0, 0);
            l0 = __builtin_amdgcn_mfma_f32_16x16x32_f16(af0, ones, l0, 0, 0, 0);
            a1 = __builtin_amdgcn_mfma_f32_16x16x32_f16(af1, bb, a1, 0, 0, 0);
            l1 = __builtin_amdgcn_mfma_f32_16x16x32_f16(af1, ones, l1, 0, 0, 0);
        }
    }
    __syncthreads();                       // mask_s/Btab2 dead; safe to overlay
#pragma unroll
    for (int reg = 0; reg < 4; ++reg) {
        accred[wv][quad * 4 + reg][m] = a0[reg];
        accred[wv][quad * 4 + reg + 16][m] = a1[reg];
    }
    if (m == 0) {
#pragma unroll
        for (int reg = 0; reg < 4; ++reg) {
            lred[wv][quad * 4 + reg] = l0[reg];
            lred[wv][quad * 4 + reg + 16] = l1[reg];
        }
    }
    __syncthreads();
    const int row = tid >> 4, col = tid & 15;
    float s0 = accred[0][row][col] + accred[1][row][col]
             + accred[2][row][col] + accred[3][row][col];
    float s1 = accred[0][row + 16][col] + accred[1][row + 16][col]
             + accred[2][row + 16][col] + accred[3][row + 16][col];
    float* op = outp + (((size_t)split * B_ + b) * N_ + i0) * EN_;
    op[(size_t)row * EN_ + col] = s0;
    op[(size_t)(row + 16) * EN_ + col] = s1;
    if (tid < 32) {
        float l = lred[0][tid] + lred[1][tid] + lred[2][tid] + lred[3][tid];
        outlp[((size_t)split * B_ + b) * N_ + i0 + tid] = l;
    }
}

// ---------- final: sum split partials, divide, ELU
__global__ __launch_bounds__(256) void finalize2_kernel(
    const float* __restrict__ outp, const float* __restrict__ outlp,
    float* __restrict__ out)
{
    const int id = blockIdx.x * 256 + threadIdx.x;      // B*N*EN
    const int gi = id >> 4;
    float num = 0.f, l = 0.f;
#pragma unroll
    for (int s = 0; s < S2_; ++s) {
        num += outp[(size_t)s * B_ * N_ * EN_ + id];
        l   += outlp[(size_t)s * B_ * N_ + gi];
    }
    float v = num / fmaxf(l, 1e-30f);
    out[id] = v > 0.f ? v : expm1f(v);
}

extern "C" void kernel_launch(void* const* d_in, const int* in_sizes, int n_in,
                              void* d_out, int out_size, void* d_ws, size_t ws_size,
                              hipStream_t stream)
{
    const float* fea = (const float*)d_in[0];
    const float* adj = (const float*)d_in[1];
    const float* Wh  = (const float*)d_in[2];
    const float* ah  = (const float*)d_in[3];
    const float* Wl  = (const float*)d_in[4];
    const float* al  = (const float*)d_in[5];

    float* p = (float*)d_ws;
    float* wh1   = p;  p += (size_t)B_ * H_ * N_;            // 32768
    float* wh2   = p;  p += (size_t)B_ * H_ * N_;            // 32768
    float* wh1b  = p;  p += (size_t)B_ * N_;                 // 8192
    float* wh2b  = p;  p += (size_t)B_ * N_;                 // 8192
    float* cmax1 = p;  p += (size_t)B_ * H_ * 128;           // 1024
    float* cmax2 = p;  p += (size_t)B_ * 256;                // 512
    float* l1p   = p;  p += (size_t)S1_ * B_ * N_ * H_;      // 131072
    float* x2p   = p;  p += (size_t)S1_ * B_ * N_ * D_;      // 4194304
    float* outp  = p;  p += (size_t)S2_ * B_ * N_ * EN_;     // 524288
    float* outlp = p;  p += (size_t)S2_ * B_ * N_;           // 32768
    unsigned long long* mask = (unsigned long long*)p;       // B*N*64 u64 = 4 MB
    unsigned short* whTt  = (unsigned short*)(mask + (size_t)B_ * N_ * 64);  // 2 MB
    unsigned short* whT2t = whTt + (size_t)B_ * H_ * 131072;                 // 256 KB

    prep_kernel<<<2048 + B_ * H_ * 128, 256, 0, stream>>>(adj, mask, fea, Wh, ah,
                                                          wh1, wh2, cmax1, whTt);
    attn1_kernel<<<dim3(N_ / 32, S1_, B_ * H_), 256, 0, stream>>>(mask, whTt, wh1, wh2,
                                                                  cmax1, x2p, l1p);
    proj2_kernel<<<dim3(N_ / 16, B_), 256, 0, stream>>>(x2p, l1p, Wl, al,
                                                        wh1b, wh2b, cmax2, whT2t);
    attn2_kernel<<<dim3(N_ / 32, S2_, B_), 256, 0, stream>>>(mask, whT2t, wh1b, wh2b, cmax2,
                                                             outp, outlp);
    finalize2_kernel<<<(B_ * N_ * EN_) / 256, 256, 0, stream>>>(outp, outlp, (float*)d_out);
}